// Round 1
// baseline (402.829 us; speedup 1.0000x reference)
//
#include <hip/hip_runtime.h>
#include <math.h>

// Problem constants (reference: B=4, S=512, E=512, H=8, DH=64, HID=128)
#define BATCH 4
#define SEQ   512
#define EMB   512
#define NH    8
#define DHD   64
#define HIDN  128
#define ALPHA 0.1f
#define EPSS  0.05f

// ---------------- tiled SGEMM: C = A[M,K] * B[N,K]^T (+bias)*scale -------
// 64x64 block tile, 256 threads, 4x4 per thread. All shapes divisible.
#define BM 64
#define BN 64
#define BK 16

__global__ __launch_bounds__(256) void gemm_nt(
    const float* __restrict__ A, const float* __restrict__ B,
    const float* __restrict__ bias, float* __restrict__ C,
    int M, int N, int K,
    long strideA, long strideB, long strideC,
    float scale, int mode)
{
    const int z = blockIdx.z;
    A += (long)z * strideA;
    B += (long)z * strideB;

    __shared__ float As[BK][BM + 4];
    __shared__ float Bs[BK][BN + 4];

    const int tid  = threadIdx.x;
    const int m0   = blockIdx.y * BM;
    const int n0   = blockIdx.x * BN;
    const int lrow = tid >> 2;          // 0..63
    const int lcol = (tid & 3) << 2;    // 0,4,8,12
    const int tm   = (tid >> 4) << 2;   // row offset 0..60
    const int tn   = (tid & 15) << 2;   // col offset 0..60

    float acc[4][4] = {};

    for (int k0 = 0; k0 < K; k0 += BK) {
        float4 av = *(const float4*)(A + (long)(m0 + lrow) * K + k0 + lcol);
        float4 bv = *(const float4*)(B + (long)(n0 + lrow) * K + k0 + lcol);
        __syncthreads();   // previous iter done reading LDS
        As[lcol + 0][lrow] = av.x; As[lcol + 1][lrow] = av.y;
        As[lcol + 2][lrow] = av.z; As[lcol + 3][lrow] = av.w;
        Bs[lcol + 0][lrow] = bv.x; Bs[lcol + 1][lrow] = bv.y;
        Bs[lcol + 2][lrow] = bv.z; Bs[lcol + 3][lrow] = bv.w;
        __syncthreads();
        #pragma unroll
        for (int k = 0; k < BK; k++) {
            float a[4], b[4];
            #pragma unroll
            for (int i = 0; i < 4; i++) a[i] = As[k][tm + i];
            #pragma unroll
            for (int j = 0; j < 4; j++) b[j] = Bs[k][tn + j];
            #pragma unroll
            for (int i = 0; i < 4; i++)
                #pragma unroll
                for (int j = 0; j < 4; j++)
                    acc[i][j] += a[i] * b[j];
        }
    }

    #pragma unroll
    for (int i = 0; i < 4; i++) {
        const int m = m0 + tm + i;
        #pragma unroll
        for (int j = 0; j < 4; j++) {
            const int n = n0 + tn + j;
            float val = acc[i][j];
            if (bias) val += bias[n];
            val *= scale;
            if (mode == 0) {
                // plain row-major
                C[(long)z * strideC + (long)m * N + n] = val;
            } else if (mode == 1) {
                // q/k: [B*S, E] -> [B,H,S,DH]
                int b = m >> 9, s = m & 511, h = n >> 6, d = n & 63;
                C[(((long)(b * NH + h)) * SEQ + s) * DHD + d] = val;
            } else if (mode == 2) {
                // v transposed: [B,H,DH,S]
                int b = m >> 9, s = m & 511, h = n >> 6, d = n & 63;
                C[(((long)(b * NH + h)) * DHD + d) * SEQ + s] = val;
            } else if (mode == 3) {
                // scores: nan_to_num + clamp +-15
                if (isnan(val)) val = 0.f;
                if (isinf(val)) val = val > 0.f ? 10.f : -10.f;
                val = fminf(fmaxf(val, -15.f), 15.f);
                C[(long)z * strideC + (long)m * N + n] = val;
            } else { // mode 4: attn@v -> out_tmp[b, s=m, h*DH+n]
                int b = z / NH, h = z % NH;
                C[((long)b * SEQ + m) * EMB + h * DHD + n] = val;
            }
        }
    }
}

// ---------------- block reduction helpers (blockDim=256, 4 waves) --------
__device__ __forceinline__ float blockReduceMax(float v, float* sred) {
    #pragma unroll
    for (int o = 32; o > 0; o >>= 1) v = fmaxf(v, __shfl_down(v, o));
    __syncthreads();
    if ((threadIdx.x & 63) == 0) sred[threadIdx.x >> 6] = v;
    __syncthreads();
    return fmaxf(fmaxf(sred[0], sred[1]), fmaxf(sred[2], sred[3]));
}
__device__ __forceinline__ float blockReduceSum(float v, float* sred) {
    #pragma unroll
    for (int o = 32; o > 0; o >>= 1) v += __shfl_down(v, o);
    __syncthreads();
    if ((threadIdx.x & 63) == 0) sred[threadIdx.x >> 6] = v;
    __syncthreads();
    return (sred[0] + sred[1]) + (sred[2] + sred[3]);
}

// ---------------- zero the per-batch accumulators ------------------------
__global__ void zero_acc(float* acc) {
    if (threadIdx.x < 16) acc[threadIdx.x] = 0.f;
}

// ---------------- transform kernel: one block per (b,i) row --------------
// computes mean-over-heads row, sig (conv chain), p-softmax -> entropy ->
// Fm-softmax, t0 = sig*Fm; accumulates per-batch {sum m, m^2, t0, t0^2}
__global__ __launch_bounds__(256) void transform_kernel(
    const float* __restrict__ scores,      // [B,H,S,S] (clamped)
    const float* __restrict__ w1, const float* __restrict__ b1,
    const float* __restrict__ w2, const float* __restrict__ b2,
    float* __restrict__ t0,                // [B,S,S]
    float* __restrict__ acc)               // [B*4]
{
    const int r = blockIdx.x;
    const int b = r >> 9, i = r & 511;
    const int tid = threadIdx.x;

    __shared__ float meanRow[SEQ];
    __shared__ float sw1[HIDN], sb1[HIDN], sw2[HIDN];
    __shared__ float sred[4];

    for (int h = tid; h < HIDN; h += 256) {
        sw1[h] = w1[h]; sb1[h] = b1[h]; sw2[h] = w2[h];
    }
    const float bb2 = b2[0];

    // mean over heads
    const float* base = scores + (((long)(b * NH)) * SEQ + i) * SEQ;
    for (int j = tid; j < SEQ; j += 256) {
        float s = 0.f;
        #pragma unroll
        for (int h = 0; h < NH; h++) s += base[(long)h * SEQ * SEQ + j];
        meanRow[j] = s * (1.0f / NH);
    }
    __syncthreads();

    float mv[2], sigv[2], mclip[2];
    float lmax = -1e30f;
    #pragma unroll
    for (int u = 0; u < 2; u++) {
        const int j = tid + u * 256;
        const float m = meanRow[j];
        mv[u] = m;
        float scaled = fminf(fmaxf(m, -8.f), 8.f) * EPSS;
        scaled = fminf(fmaxf(scaled, -10.f), 10.f);
        float a = 0.f;
        for (int h2 = 0; h2 < HIDN; h2++) {
            float hv = scaled * sw1[h2] + sb1[h2];
            hv = fminf(fmaxf(hv, -5.f), 5.f);
            hv = fmaxf(hv, 0.f);
            a += hv * sw2[h2];
        }
        a += bb2;
        a = fminf(fmaxf(a, -5.f), 5.f);
        const float taylor = fminf(fmaxf(1.f + 2.5f * a, 0.5f), 1.5f);
        sigv[u] = 1.f / (1.f + expf(-taylor));
        const float mc = fminf(fmaxf(m, -10.f), 10.f);
        mclip[u] = mc;
        lmax = fmaxf(lmax, mc);
    }

    // p = softmax(mclip)
    const float rmax = blockReduceMax(lmax, sred);
    float ex[2], lsum = 0.f;
    #pragma unroll
    for (int u = 0; u < 2; u++) { ex[u] = expf(mclip[u] - rmax); lsum += ex[u]; }
    const float rsum = blockReduceSum(lsum, sred);
    const float inv = 1.f / rsum;

    // Hent -> Fm = softmax(3*Hent)
    float hent[2], lmax2 = -1e30f;
    #pragma unroll
    for (int u = 0; u < 2; u++) {
        const float p = ex[u] * inv;
        const float he = -p * logf(p + 1e-6f);
        hent[u] = 3.f * he;
        lmax2 = fmaxf(lmax2, hent[u]);
    }
    const float rmax2 = blockReduceMax(lmax2, sred);
    float ex2[2], lsum2 = 0.f;
    #pragma unroll
    for (int u = 0; u < 2; u++) { ex2[u] = expf(hent[u] - rmax2); lsum2 += ex2[u]; }
    const float rsum2 = blockReduceSum(lsum2, sred);
    const float inv2 = 1.f / rsum2;

    float s_m = 0.f, s_m2 = 0.f, s_t = 0.f, s_t2 = 0.f;
    #pragma unroll
    for (int u = 0; u < 2; u++) {
        const int j = tid + u * 256;
        const float Fm = ex2[u] * inv2;
        const float tv = sigv[u] * Fm;
        t0[((long)b * SEQ + i) * SEQ + j] = tv;
        s_m += mv[u]; s_m2 += mv[u] * mv[u];
        s_t += tv;    s_t2 += tv * tv;
    }
    s_m  = blockReduceSum(s_m,  sred);
    s_m2 = blockReduceSum(s_m2, sred);
    s_t  = blockReduceSum(s_t,  sred);
    s_t2 = blockReduceSum(s_t2, sred);
    if (tid == 0) {
        atomicAdd(&acc[b * 4 + 0], s_m);
        atomicAdd(&acc[b * 4 + 1], s_m2);
        atomicAdd(&acc[b * 4 + 2], s_t);
        atomicAdd(&acc[b * 4 + 3], s_t2);
    }
}

// ---------------- per-batch scalar stats -> c0,c1 ------------------------
__global__ void stats_kernel(const float* __restrict__ acc, float* __restrict__ coef) {
    const int b = threadIdx.x;
    if (b < BATCH) {
        const float sm = acc[b * 4 + 0], sm2 = acc[b * 4 + 1];
        const float st = acc[b * 4 + 2], st2 = acc[b * 4 + 3];
        const float n = (float)SEQ * (float)SEQ;
        const float e_o = sqrtf(sm2) + 1e-4f;
        const float e_t = sqrtf(st2) + 1e-4f;
        const float gamma = fminf(fmaxf(e_o / e_t, 0.8f), 1.2f);
        const float o_mean = sm / n, t0m = st / n;
        const float o_var = fmaxf(sm2 / n - o_mean * o_mean, 0.f);
        const float o_std = sqrtf(fmaxf(o_var, 0.01f));
        const float t0var = fmaxf(st2 / n - t0m * t0m, 0.f);
        const float t_std = sqrtf(fmaxf(gamma * gamma * t0var, 0.01f));
        const float gdyn = fminf(fmaxf(o_std / t_std, 0.8f), 1.2f);
        const float c1 = gdyn * gamma;
        coef[b] = o_mean - c1 * t0m;   // c0
        coef[BATCH + b] = c1;          // c1
    }
}

// ---------------- residual + final clamp + softmax (in place) ------------
__global__ __launch_bounds__(256) void softmax_kernel(
    float* __restrict__ scores,            // [B,H,S,S] in -> attn out
    const float* __restrict__ t0,          // [B,S,S]
    const float* __restrict__ coef)        // c0[B], c1[B]
{
    const int r = blockIdx.x;              // (b*H+h)*S + i
    const int i = r & 511;
    const int bh = r >> 9;
    const int b = bh >> 3;
    const float c0 = coef[b], c1 = coef[BATCH + b];
    float* row = scores + (long)r * SEQ;
    const float* trow = t0 + ((long)b * SEQ + i) * SEQ;
    const int tid = threadIdx.x;
    __shared__ float sred[4];

    float v[2], lmax = -1e30f;
    #pragma unroll
    for (int u = 0; u < 2; u++) {
        const int j = tid + u * 256;
        float sv = row[j] + ALPHA * (c0 + c1 * trow[j]);
        sv = fminf(fmaxf(sv, -15.f), 15.f);
        v[u] = sv;
        lmax = fmaxf(lmax, sv);
    }
    const float rmax = blockReduceMax(lmax, sred);
    float ex[2], lsum = 0.f;
    #pragma unroll
    for (int u = 0; u < 2; u++) { ex[u] = expf(v[u] - rmax); lsum += ex[u]; }
    const float rsum = blockReduceSum(lsum, sred);
    const float inv = 1.f / rsum;
    #pragma unroll
    for (int u = 0; u < 2; u++) row[tid + u * 256] = ex[u] * inv;
}

// -------------------------------------------------------------------------
extern "C" void kernel_launch(void* const* d_in, const int* in_sizes, int n_in,
                              void* d_out, int out_size, void* d_ws, size_t ws_size,
                              hipStream_t stream) {
    const float* x  = (const float*)d_in[0];
    const float* wq = (const float*)d_in[1];
    const float* bq = (const float*)d_in[2];
    const float* wk = (const float*)d_in[3];
    const float* bk = (const float*)d_in[4];
    const float* wv = (const float*)d_in[5];
    const float* bv = (const float*)d_in[6];
    const float* wo = (const float*)d_in[7];
    const float* bo = (const float*)d_in[8];
    const float* w1 = (const float*)d_in[9];
    const float* b1 = (const float*)d_in[10];
    const float* w2 = (const float*)d_in[11];
    const float* b2 = (const float*)d_in[12];
    float* out = (float*)d_out;

    // workspace layout (floats); total ~50.3 MB
    float* ws      = (float*)d_ws;
    float* qbuf    = ws;                       // [B,H,S,DH]   1M
    float* kbuf    = qbuf + 1048576;           // [B,H,S,DH]   1M
    float* vT      = kbuf + 1048576;           // [B,H,DH,S]   1M
    float* scores  = vT + 1048576;             // [B,H,S,S]    8M
    float* t0      = scores + 8388608;         // [B,S,S]      1M
    float* accv    = t0 + 1048576;             // 16
    float* coef    = accv + 16;                // 8
    float* out_tmp = qbuf;                     // reuse qbuf after attn@v

    const int MROWS = BATCH * SEQ;   // 2048
    const float scaling = 0.125f;    // DH^-0.5

    zero_acc<<<dim3(1), dim3(64), 0, stream>>>(accv);

    // QKV projections
    gemm_nt<<<dim3(EMB / BN, MROWS / BM, 1), dim3(256), 0, stream>>>(
        x, wq, bq, qbuf, MROWS, EMB, EMB, 0, 0, 0, scaling, 1);
    gemm_nt<<<dim3(EMB / BN, MROWS / BM, 1), dim3(256), 0, stream>>>(
        x, wk, bk, kbuf, MROWS, EMB, EMB, 0, 0, 0, 1.f, 1);
    gemm_nt<<<dim3(EMB / BN, MROWS / BM, 1), dim3(256), 0, stream>>>(
        x, wv, bv, vT, MROWS, EMB, EMB, 0, 0, 0, 1.f, 2);

    // scores = q @ k^T per (b,h), clamp
    gemm_nt<<<dim3(SEQ / BN, SEQ / BM, BATCH * NH), dim3(256), 0, stream>>>(
        qbuf, kbuf, nullptr, scores, SEQ, SEQ, DHD,
        (long)SEQ * DHD, (long)SEQ * DHD, (long)SEQ * SEQ, 1.f, 3);

    // autopoietic transform row kernel
    transform_kernel<<<dim3(BATCH * SEQ), dim3(256), 0, stream>>>(
        scores, w1, b1, w2, b2, t0, accv);

    stats_kernel<<<dim3(1), dim3(64), 0, stream>>>(accv, coef);

    // residual + clamp + softmax (scores -> attn in place)
    softmax_kernel<<<dim3(BATCH * NH * SEQ), dim3(256), 0, stream>>>(
        scores, t0, coef);

    // out_tmp[b,s,e] = attn @ v
    gemm_nt<<<dim3(DHD / BN, SEQ / BM, BATCH * NH), dim3(256), 0, stream>>>(
        scores, vT, nullptr, out_tmp, SEQ, DHD, SEQ,
        (long)SEQ * SEQ, (long)DHD * SEQ, 0, 1.f, 4);

    // final projection
    gemm_nt<<<dim3(EMB / BN, MROWS / BM, 1), dim3(256), 0, stream>>>(
        out_tmp, wo, bo, out, MROWS, EMB, EMB, 0, 0, 0, 1.f, 0);
}

// Round 2
// 393.587 us; speedup vs baseline: 1.0235x; 1.0235x over previous
//
#include <hip/hip_runtime.h>
#include <math.h>

// Problem constants (reference: B=4, S=512, E=512, H=8, DH=64, HID=128)
#define BATCH 4
#define SEQ   512
#define EMB   512
#define NH    8
#define DHD   64
#define HIDN  128
#define ALPHA 0.1f
#define EPSS  0.05f

// LUT for the pointwise conv-chain -> sigmoid function of `scaled`
#define LUTN  2048
#define XMIN  (-0.4f)
#define XSTEP (0.8f / LUTN)

// ---------------- tiled SGEMM: C = A[M,K] * B[N,K]^T (+bias)*scale -------
// 64x64 block tile, 256 threads, 4x4 per thread. All shapes divisible.
#define BM 64
#define BN 64
#define BK 16

__global__ __launch_bounds__(256) void gemm_nt(
    const float* __restrict__ A, const float* __restrict__ B,
    const float* __restrict__ bias, float* __restrict__ C,
    int M, int N, int K,
    long strideA, long strideB, long strideC,
    float scale, int mode)
{
    const int z = blockIdx.z;
    A += (long)z * strideA;
    B += (long)z * strideB;

    __shared__ float As[BK][BM + 4];
    __shared__ float Bs[BK][BN + 4];

    const int tid  = threadIdx.x;
    const int m0   = blockIdx.y * BM;
    const int n0   = blockIdx.x * BN;
    const int lrow = tid >> 2;          // 0..63
    const int lcol = (tid & 3) << 2;    // 0,4,8,12
    const int tm   = (tid >> 4) << 2;   // row offset 0..60
    const int tn   = (tid & 15) << 2;   // col offset 0..60

    float acc[4][4] = {};

    for (int k0 = 0; k0 < K; k0 += BK) {
        float4 av = *(const float4*)(A + (long)(m0 + lrow) * K + k0 + lcol);
        float4 bv = *(const float4*)(B + (long)(n0 + lrow) * K + k0 + lcol);
        __syncthreads();   // previous iter done reading LDS
        As[lcol + 0][lrow] = av.x; As[lcol + 1][lrow] = av.y;
        As[lcol + 2][lrow] = av.z; As[lcol + 3][lrow] = av.w;
        Bs[lcol + 0][lrow] = bv.x; Bs[lcol + 1][lrow] = bv.y;
        Bs[lcol + 2][lrow] = bv.z; Bs[lcol + 3][lrow] = bv.w;
        __syncthreads();
        #pragma unroll
        for (int k = 0; k < BK; k++) {
            float a[4], b[4];
            #pragma unroll
            for (int i = 0; i < 4; i++) a[i] = As[k][tm + i];
            #pragma unroll
            for (int j = 0; j < 4; j++) b[j] = Bs[k][tn + j];
            #pragma unroll
            for (int i = 0; i < 4; i++)
                #pragma unroll
                for (int j = 0; j < 4; j++)
                    acc[i][j] += a[i] * b[j];
        }
    }

    #pragma unroll
    for (int i = 0; i < 4; i++) {
        const int m = m0 + tm + i;
        #pragma unroll
        for (int j = 0; j < 4; j++) {
            const int n = n0 + tn + j;
            float val = acc[i][j];
            if (bias) val += bias[n];
            val *= scale;
            if (mode == 0) {
                // plain row-major
                C[(long)z * strideC + (long)m * N + n] = val;
            } else if (mode == 1) {
                // q/k: [B*S, E] -> [B,H,S,DH]
                int b = m >> 9, s = m & 511, h = n >> 6, d = n & 63;
                C[(((long)(b * NH + h)) * SEQ + s) * DHD + d] = val;
            } else if (mode == 2) {
                // v transposed: [B,H,DH,S]
                int b = m >> 9, s = m & 511, h = n >> 6, d = n & 63;
                C[(((long)(b * NH + h)) * DHD + d) * SEQ + s] = val;
            } else if (mode == 3) {
                // scores: nan_to_num + clamp +-15
                if (isnan(val)) val = 0.f;
                if (isinf(val)) val = val > 0.f ? 10.f : -10.f;
                val = fminf(fmaxf(val, -15.f), 15.f);
                C[(long)z * strideC + (long)m * N + n] = val;
            } else { // mode 4: attn@v -> out_tmp[b, s=m, h*DH+n]
                int b = z / NH, h = z % NH;
                C[((long)b * SEQ + m) * EMB + h * DHD + n] = val;
            }
        }
    }
}

// ---------------- block reduction helpers (blockDim=256, 4 waves) --------
__device__ __forceinline__ float blockReduceMax(float v, float* sred) {
    #pragma unroll
    for (int o = 32; o > 0; o >>= 1) v = fmaxf(v, __shfl_down(v, o));
    __syncthreads();
    if ((threadIdx.x & 63) == 0) sred[threadIdx.x >> 6] = v;
    __syncthreads();
    return fmaxf(fmaxf(sred[0], sred[1]), fmaxf(sred[2], sred[3]));
}
__device__ __forceinline__ float blockReduceSum(float v, float* sred) {
    #pragma unroll
    for (int o = 32; o > 0; o >>= 1) v += __shfl_down(v, o);
    __syncthreads();
    if ((threadIdx.x & 63) == 0) sred[threadIdx.x >> 6] = v;
    __syncthreads();
    return (sred[0] + sred[1]) + (sred[2] + sred[3]);
}

// ---------------- zero the per-batch accumulators ------------------------
__global__ void zero_acc(float* acc) {
    if (threadIdx.x < 16) acc[threadIdx.x] = 0.f;
}

// ---------------- build the pointwise-function LUT -----------------------
// lut[i] = sigmoid(clip(1 + 2.5*clip(sum_h w2[h]*relu(clip(w1[h]*x+b1[h],-5,5)) + b2, -5,5), 0.5,1.5))
// for x = XMIN + i*XSTEP, i in [0, LUTN]. Function is piecewise-linear with
// tiny slope jumps (<0.05) at breakpoints -> lerp error ~5e-6, negligible
// after *2.5*sigmoid'*Fm(~1/512)*alpha.
__global__ void build_lut(
    const float* __restrict__ w1, const float* __restrict__ b1,
    const float* __restrict__ w2, const float* __restrict__ b2,
    float* __restrict__ lut)
{
    const int i = blockIdx.x * blockDim.x + threadIdx.x;
    if (i > LUTN) return;
    const float x = XMIN + i * XSTEP;
    float a = 0.f;
    for (int h = 0; h < HIDN; h++) {
        float hv = x * w1[h] + b1[h];
        hv = fminf(fmaxf(hv, -5.f), 5.f);
        hv = fmaxf(hv, 0.f);
        a += hv * w2[h];
    }
    a += b2[0];
    a = fminf(fmaxf(a, -5.f), 5.f);
    const float taylor = fminf(fmaxf(1.f + 2.5f * a, 0.5f), 1.5f);
    lut[i] = 1.f / (1.f + expf(-taylor));
}

// ---------------- transform kernel: one block per (b,i) row --------------
// mean-over-heads row, sig via LUT lerp, p-softmax -> entropy -> Fm-softmax,
// t0 = sig*Fm; accumulates per-batch {sum m, m^2, t0, t0^2}
__global__ __launch_bounds__(256) void transform_kernel(
    const float* __restrict__ scores,      // [B,H,S,S] (clamped)
    const float* __restrict__ lut,         // [LUTN+1]
    float* __restrict__ t0,                // [B,S,S]
    float* __restrict__ acc)               // [B*4]
{
    const int r = blockIdx.x;
    const int b = r >> 9, i = r & 511;
    const int tid = threadIdx.x;

    __shared__ float slut[LUTN + 1];
    __shared__ float sred[4];

    for (int u = tid; u <= LUTN; u += 256) slut[u] = lut[u];

    const float* base = scores + (((long)(b * NH)) * SEQ + i) * SEQ;

    float mv[2], sigv[2], mclip[2];
    float lmax = -1e30f;
    __syncthreads();
    #pragma unroll
    for (int u = 0; u < 2; u++) {
        const int j = tid + u * 256;
        float s = 0.f;
        #pragma unroll
        for (int h = 0; h < NH; h++) s += base[(long)h * SEQ * SEQ + j];
        const float m = s * (1.0f / NH);
        mv[u] = m;
        // scaled in [-0.4, 0.4] -> LUT lerp
        const float x = fminf(fmaxf(m, -8.f), 8.f) * EPSS;
        float t = (x - XMIN) * (1.0f / XSTEP);
        int idx = (int)t;
        idx = idx < 0 ? 0 : (idx > LUTN - 1 ? LUTN - 1 : idx);
        const float frac = t - (float)idx;
        const float l0 = slut[idx], l1 = slut[idx + 1];
        sigv[u] = l0 + frac * (l1 - l0);
        const float mc = fminf(fmaxf(m, -10.f), 10.f);
        mclip[u] = mc;
        lmax = fmaxf(lmax, mc);
    }

    // p = softmax(mclip)
    const float rmax = blockReduceMax(lmax, sred);
    float ex[2], lsum = 0.f;
    #pragma unroll
    for (int u = 0; u < 2; u++) { ex[u] = expf(mclip[u] - rmax); lsum += ex[u]; }
    const float rsum = blockReduceSum(lsum, sred);
    const float inv = 1.f / rsum;

    // Hent -> Fm = softmax(3*Hent)
    float hent[2], lmax2 = -1e30f;
    #pragma unroll
    for (int u = 0; u < 2; u++) {
        const float p = ex[u] * inv;
        const float he = -p * logf(p + 1e-6f);
        hent[u] = 3.f * he;
        lmax2 = fmaxf(lmax2, hent[u]);
    }
    const float rmax2 = blockReduceMax(lmax2, sred);
    float ex2[2], lsum2 = 0.f;
    #pragma unroll
    for (int u = 0; u < 2; u++) { ex2[u] = expf(hent[u] - rmax2); lsum2 += ex2[u]; }
    const float rsum2 = blockReduceSum(lsum2, sred);
    const float inv2 = 1.f / rsum2;

    float s_m = 0.f, s_m2 = 0.f, s_t = 0.f, s_t2 = 0.f;
    #pragma unroll
    for (int u = 0; u < 2; u++) {
        const int j = tid + u * 256;
        const float Fm = ex2[u] * inv2;
        const float tv = sigv[u] * Fm;
        t0[((long)b * SEQ + i) * SEQ + j] = tv;
        s_m += mv[u]; s_m2 += mv[u] * mv[u];
        s_t += tv;    s_t2 += tv * tv;
    }
    s_m  = blockReduceSum(s_m,  sred);
    s_m2 = blockReduceSum(s_m2, sred);
    s_t  = blockReduceSum(s_t,  sred);
    s_t2 = blockReduceSum(s_t2, sred);
    if (tid == 0) {
        atomicAdd(&acc[b * 4 + 0], s_m);
        atomicAdd(&acc[b * 4 + 1], s_m2);
        atomicAdd(&acc[b * 4 + 2], s_t);
        atomicAdd(&acc[b * 4 + 3], s_t2);
    }
}

// ---------------- per-batch scalar stats -> c0,c1 ------------------------
__global__ void stats_kernel(const float* __restrict__ acc, float* __restrict__ coef) {
    const int b = threadIdx.x;
    if (b < BATCH) {
        const float sm = acc[b * 4 + 0], sm2 = acc[b * 4 + 1];
        const float st = acc[b * 4 + 2], st2 = acc[b * 4 + 3];
        const float n = (float)SEQ * (float)SEQ;
        const float e_o = sqrtf(sm2) + 1e-4f;
        const float e_t = sqrtf(st2) + 1e-4f;
        const float gamma = fminf(fmaxf(e_o / e_t, 0.8f), 1.2f);
        const float o_mean = sm / n, t0m = st / n;
        const float o_var = fmaxf(sm2 / n - o_mean * o_mean, 0.f);
        const float o_std = sqrtf(fmaxf(o_var, 0.01f));
        const float t0var = fmaxf(st2 / n - t0m * t0m, 0.f);
        const float t_std = sqrtf(fmaxf(gamma * gamma * t0var, 0.01f));
        const float gdyn = fminf(fmaxf(o_std / t_std, 0.8f), 1.2f);
        const float c1 = gdyn * gamma;
        coef[b] = o_mean - c1 * t0m;   // c0
        coef[BATCH + b] = c1;          // c1
    }
}

// ---------------- residual + final clamp + softmax (in place) ------------
__global__ __launch_bounds__(256) void softmax_kernel(
    float* __restrict__ scores,            // [B,H,S,S] in -> attn out
    const float* __restrict__ t0,          // [B,S,S]
    const float* __restrict__ coef)        // c0[B], c1[B]
{
    const int r = blockIdx.x;              // (b*H+h)*S + i
    const int i = r & 511;
    const int bh = r >> 9;
    const int b = bh >> 3;
    const float c0 = coef[b], c1 = coef[BATCH + b];
    float* row = scores + (long)r * SEQ;
    const float* trow = t0 + ((long)b * SEQ + i) * SEQ;
    const int tid = threadIdx.x;
    __shared__ float sred[4];

    float v[2], lmax = -1e30f;
    #pragma unroll
    for (int u = 0; u < 2; u++) {
        const int j = tid + u * 256;
        float sv = row[j] + ALPHA * (c0 + c1 * trow[j]);
        sv = fminf(fmaxf(sv, -15.f), 15.f);
        v[u] = sv;
        lmax = fmaxf(lmax, sv);
    }
    const float rmax = blockReduceMax(lmax, sred);
    float ex[2], lsum = 0.f;
    #pragma unroll
    for (int u = 0; u < 2; u++) { ex[u] = expf(v[u] - rmax); lsum += ex[u]; }
    const float rsum = blockReduceSum(lsum, sred);
    const float inv = 1.f / rsum;
    #pragma unroll
    for (int u = 0; u < 2; u++) row[tid + u * 256] = ex[u] * inv;
}

// -------------------------------------------------------------------------
extern "C" void kernel_launch(void* const* d_in, const int* in_sizes, int n_in,
                              void* d_out, int out_size, void* d_ws, size_t ws_size,
                              hipStream_t stream) {
    const float* x  = (const float*)d_in[0];
    const float* wq = (const float*)d_in[1];
    const float* bq = (const float*)d_in[2];
    const float* wk = (const float*)d_in[3];
    const float* bk = (const float*)d_in[4];
    const float* wv = (const float*)d_in[5];
    const float* bv = (const float*)d_in[6];
    const float* wo = (const float*)d_in[7];
    const float* bo = (const float*)d_in[8];
    const float* w1 = (const float*)d_in[9];
    const float* b1 = (const float*)d_in[10];
    const float* w2 = (const float*)d_in[11];
    const float* b2 = (const float*)d_in[12];
    float* out = (float*)d_out;

    // workspace layout (floats); total ~50.3 MB
    float* ws      = (float*)d_ws;
    float* qbuf    = ws;                       // [B,H,S,DH]   1M
    float* kbuf    = qbuf + 1048576;           // [B,H,S,DH]   1M
    float* vT      = kbuf + 1048576;           // [B,H,DH,S]   1M
    float* scores  = vT + 1048576;             // [B,H,S,S]    8M
    float* t0      = scores + 8388608;         // [B,S,S]      1M
    float* accv    = t0 + 1048576;             // 16
    float* coef    = accv + 16;                // 8
    float* lutbuf  = coef + 8;                 // LUTN+1
    float* out_tmp = qbuf;                     // reuse qbuf after attn@v

    const int MROWS = BATCH * SEQ;   // 2048
    const float scaling = 0.125f;    // DH^-0.5

    zero_acc<<<dim3(1), dim3(64), 0, stream>>>(accv);
    build_lut<<<dim3((LUTN + 256) / 256), dim3(256), 0, stream>>>(w1, b1, w2, b2, lutbuf);

    // QKV projections
    gemm_nt<<<dim3(EMB / BN, MROWS / BM, 1), dim3(256), 0, stream>>>(
        x, wq, bq, qbuf, MROWS, EMB, EMB, 0, 0, 0, scaling, 1);
    gemm_nt<<<dim3(EMB / BN, MROWS / BM, 1), dim3(256), 0, stream>>>(
        x, wk, bk, kbuf, MROWS, EMB, EMB, 0, 0, 0, 1.f, 1);
    gemm_nt<<<dim3(EMB / BN, MROWS / BM, 1), dim3(256), 0, stream>>>(
        x, wv, bv, vT, MROWS, EMB, EMB, 0, 0, 0, 1.f, 2);

    // scores = q @ k^T per (b,h), clamp
    gemm_nt<<<dim3(SEQ / BN, SEQ / BM, BATCH * NH), dim3(256), 0, stream>>>(
        qbuf, kbuf, nullptr, scores, SEQ, SEQ, DHD,
        (long)SEQ * DHD, (long)SEQ * DHD, (long)SEQ * SEQ, 1.f, 3);

    // autopoietic transform row kernel (LUT-based)
    transform_kernel<<<dim3(BATCH * SEQ), dim3(256), 0, stream>>>(
        scores, lutbuf, t0, accv);

    stats_kernel<<<dim3(1), dim3(64), 0, stream>>>(accv, coef);

    // residual + clamp + softmax (scores -> attn in place)
    softmax_kernel<<<dim3(BATCH * NH * SEQ), dim3(256), 0, stream>>>(
        scores, t0, coef);

    // out_tmp[b,s,e] = attn @ v
    gemm_nt<<<dim3(DHD / BN, SEQ / BM, BATCH * NH), dim3(256), 0, stream>>>(
        scores, vT, nullptr, out_tmp, SEQ, DHD, SEQ,
        (long)SEQ * SEQ, (long)DHD * SEQ, 0, 1.f, 4);

    // final projection
    gemm_nt<<<dim3(EMB / BN, MROWS / BM, 1), dim3(256), 0, stream>>>(
        out_tmp, wo, bo, out, MROWS, EMB, EMB, 0, 0, 0, 1.f, 0);
}

// Round 3
// 294.213 us; speedup vs baseline: 1.3692x; 1.3378x over previous
//
#include <hip/hip_runtime.h>
#include <math.h>

// Problem constants (reference: B=4, S=512, E=512, H=8, DH=64, HID=128)
#define BATCH 4
#define SEQ   512
#define EMB   512
#define NH    8
#define DHD   64
#define HIDN  128
#define ALPHA 0.1f
#define EPSS  0.05f

// LUT for the pointwise conv-chain -> sigmoid function of `scaled`
#define LUTN  2048
#define XMIN  (-0.4f)
#define XSTEP (0.8f / LUTN)

// ---------------- tiled SGEMM: C = A[M,K] * B[N,K]^T (+bias)*scale -------
// 64x64 block tile, 256 threads, 4x4 per thread. All shapes divisible.
#define BM 64
#define BN 64
#define BK 16

__global__ __launch_bounds__(256) void gemm_nt(
    const float* __restrict__ A, const float* __restrict__ B,
    const float* __restrict__ bias, float* __restrict__ C,
    int M, int N, int K,
    long strideA, long strideB, long strideC,
    float scale, int mode)
{
    const int z = blockIdx.z;
    A += (long)z * strideA;
    B += (long)z * strideB;

    __shared__ float As[BK][BM + 4];
    __shared__ float Bs[BK][BN + 4];

    const int tid  = threadIdx.x;
    const int m0   = blockIdx.y * BM;
    const int n0   = blockIdx.x * BN;
    const int lrow = tid >> 2;          // 0..63
    const int lcol = (tid & 3) << 2;    // 0,4,8,12
    const int tm   = (tid >> 4) << 2;   // row offset 0..60
    const int tn   = (tid & 15) << 2;   // col offset 0..60

    float acc[4][4] = {};

    for (int k0 = 0; k0 < K; k0 += BK) {
        float4 av = *(const float4*)(A + (long)(m0 + lrow) * K + k0 + lcol);
        float4 bv = *(const float4*)(B + (long)(n0 + lrow) * K + k0 + lcol);
        __syncthreads();   // previous iter done reading LDS
        As[lcol + 0][lrow] = av.x; As[lcol + 1][lrow] = av.y;
        As[lcol + 2][lrow] = av.z; As[lcol + 3][lrow] = av.w;
        Bs[lcol + 0][lrow] = bv.x; Bs[lcol + 1][lrow] = bv.y;
        Bs[lcol + 2][lrow] = bv.z; Bs[lcol + 3][lrow] = bv.w;
        __syncthreads();
        #pragma unroll
        for (int k = 0; k < BK; k++) {
            float a[4], b[4];
            #pragma unroll
            for (int i = 0; i < 4; i++) a[i] = As[k][tm + i];
            #pragma unroll
            for (int j = 0; j < 4; j++) b[j] = Bs[k][tn + j];
            #pragma unroll
            for (int i = 0; i < 4; i++)
                #pragma unroll
                for (int j = 0; j < 4; j++)
                    acc[i][j] += a[i] * b[j];
        }
    }

    #pragma unroll
    for (int i = 0; i < 4; i++) {
        const int m = m0 + tm + i;
        #pragma unroll
        for (int j = 0; j < 4; j++) {
            const int n = n0 + tn + j;
            float val = acc[i][j];
            if (bias) val += bias[n];
            val *= scale;
            if (mode == 0) {
                // plain row-major
                C[(long)z * strideC + (long)m * N + n] = val;
            } else if (mode == 1) {
                // q/k: [B*S, E] -> [B,H,S,DH]
                int b = m >> 9, s = m & 511, h = n >> 6, d = n & 63;
                C[(((long)(b * NH + h)) * SEQ + s) * DHD + d] = val;
            } else if (mode == 2) {
                // v transposed: [B,H,DH,S]
                int b = m >> 9, s = m & 511, h = n >> 6, d = n & 63;
                C[(((long)(b * NH + h)) * DHD + d) * SEQ + s] = val;
            } else if (mode == 3) {
                // scores: nan_to_num + clamp +-15
                if (isnan(val)) val = 0.f;
                if (isinf(val)) val = val > 0.f ? 10.f : -10.f;
                val = fminf(fmaxf(val, -15.f), 15.f);
                C[(long)z * strideC + (long)m * N + n] = val;
            } else { // mode 4: attn@v -> out_tmp[b, s=m, h*DH+n]
                int b = z / NH, h = z % NH;
                C[((long)b * SEQ + m) * EMB + h * DHD + n] = val;
            }
        }
    }
}

// ---------------- block reduction helpers (blockDim=256, 4 waves) --------
__device__ __forceinline__ float blockReduceMax(float v, float* sred) {
    #pragma unroll
    for (int o = 32; o > 0; o >>= 1) v = fmaxf(v, __shfl_down(v, o));
    __syncthreads();
    if ((threadIdx.x & 63) == 0) sred[threadIdx.x >> 6] = v;
    __syncthreads();
    return fmaxf(fmaxf(sred[0], sred[1]), fmaxf(sred[2], sred[3]));
}
__device__ __forceinline__ float blockReduceSum(float v, float* sred) {
    #pragma unroll
    for (int o = 32; o > 0; o >>= 1) v += __shfl_down(v, o);
    __syncthreads();
    if ((threadIdx.x & 63) == 0) sred[threadIdx.x >> 6] = v;
    __syncthreads();
    return (sred[0] + sred[1]) + (sred[2] + sred[3]);
}

// ---------------- build the pointwise-function LUT -----------------------
// lut[i] = sigmoid(clip(1 + 2.5*clip(sum_h w2[h]*relu(clip(w1[h]*x+b1[h],-5,5)) + b2, -5,5), 0.5,1.5))
// for x = XMIN + i*XSTEP, i in [0, LUTN]. Piecewise-linear with tiny slope
// jumps -> lerp error ~5e-6 in `auto`, negligible downstream.
__global__ void build_lut(
    const float* __restrict__ w1, const float* __restrict__ b1,
    const float* __restrict__ w2, const float* __restrict__ b2,
    float* __restrict__ lut)
{
    const int i = blockIdx.x * blockDim.x + threadIdx.x;
    if (i > LUTN) return;
    const float x = XMIN + i * XSTEP;
    float a = 0.f;
    for (int h = 0; h < HIDN; h++) {
        float hv = x * w1[h] + b1[h];
        hv = fminf(fmaxf(hv, -5.f), 5.f);
        hv = fmaxf(hv, 0.f);
        a += hv * w2[h];
    }
    a += b2[0];
    a = fminf(fmaxf(a, -5.f), 5.f);
    const float taylor = fminf(fmaxf(1.f + 2.5f * a, 0.5f), 1.5f);
    lut[i] = 1.f / (1.f + expf(-taylor));
}

// ---------------- transform kernel: one block per (b,i) row --------------
// mean-over-heads row, sig via LUT lerp, p-softmax -> entropy -> Fm-softmax,
// t0 = sig*Fm; writes per-block partial {sum m, m^2, t0, t0^2} to its OWN
// slot (no atomics -- 8192 same-line device atomics were a ~100us serial
// tail in rounds 1-2).
__global__ __launch_bounds__(256) void transform_kernel(
    const float* __restrict__ scores,      // [B,H,S,S] (clamped)
    const float* __restrict__ lut,         // [LUTN+1]
    float* __restrict__ t0,                // [B,S,S]
    float4* __restrict__ partials)         // [B*S] float4 slots
{
    const int r = blockIdx.x;
    const int b = r >> 9, i = r & 511;
    const int tid = threadIdx.x;

    __shared__ float slut[LUTN + 1];
    __shared__ float sred[4];

    for (int u = tid; u <= LUTN; u += 256) slut[u] = lut[u];

    const float* base = scores + (((long)(b * NH)) * SEQ + i) * SEQ;

    float mv[2], sigv[2], mclip[2];
    float lmax = -1e30f;
    __syncthreads();
    #pragma unroll
    for (int u = 0; u < 2; u++) {
        const int j = tid + u * 256;
        float s = 0.f;
        #pragma unroll
        for (int h = 0; h < NH; h++) s += base[(long)h * SEQ * SEQ + j];
        const float m = s * (1.0f / NH);
        mv[u] = m;
        // scaled in [-0.4, 0.4] -> LUT lerp
        const float x = fminf(fmaxf(m, -8.f), 8.f) * EPSS;
        float t = (x - XMIN) * (1.0f / XSTEP);
        int idx = (int)t;
        idx = idx < 0 ? 0 : (idx > LUTN - 1 ? LUTN - 1 : idx);
        const float frac = t - (float)idx;
        const float l0 = slut[idx], l1 = slut[idx + 1];
        sigv[u] = l0 + frac * (l1 - l0);
        const float mc = fminf(fmaxf(m, -10.f), 10.f);
        mclip[u] = mc;
        lmax = fmaxf(lmax, mc);
    }

    // p = softmax(mclip)
    const float rmax = blockReduceMax(lmax, sred);
    float ex[2], lsum = 0.f;
    #pragma unroll
    for (int u = 0; u < 2; u++) { ex[u] = expf(mclip[u] - rmax); lsum += ex[u]; }
    const float rsum = blockReduceSum(lsum, sred);
    const float inv = 1.f / rsum;

    // Hent -> Fm = softmax(3*Hent)
    float hent[2], lmax2 = -1e30f;
    #pragma unroll
    for (int u = 0; u < 2; u++) {
        const float p = ex[u] * inv;
        const float he = -p * logf(p + 1e-6f);
        hent[u] = 3.f * he;
        lmax2 = fmaxf(lmax2, hent[u]);
    }
    const float rmax2 = blockReduceMax(lmax2, sred);
    float ex2[2], lsum2 = 0.f;
    #pragma unroll
    for (int u = 0; u < 2; u++) { ex2[u] = expf(hent[u] - rmax2); lsum2 += ex2[u]; }
    const float rsum2 = blockReduceSum(lsum2, sred);
    const float inv2 = 1.f / rsum2;

    float s_m = 0.f, s_m2 = 0.f, s_t = 0.f, s_t2 = 0.f;
    #pragma unroll
    for (int u = 0; u < 2; u++) {
        const int j = tid + u * 256;
        const float Fm = ex2[u] * inv2;
        const float tv = sigv[u] * Fm;
        t0[((long)b * SEQ + i) * SEQ + j] = tv;
        s_m += mv[u]; s_m2 += mv[u] * mv[u];
        s_t += tv;    s_t2 += tv * tv;
    }
    s_m  = blockReduceSum(s_m,  sred);
    s_m2 = blockReduceSum(s_m2, sred);
    s_t  = blockReduceSum(s_t,  sred);
    s_t2 = blockReduceSum(s_t2, sred);
    if (tid == 0) {
        partials[r] = make_float4(s_m, s_m2, s_t, s_t2);
    }
}

// ---------------- per-batch stats reduction -> c0,c1 ---------------------
// grid = BATCH blocks x 256 threads; reduces 512 float4 partials per batch.
__global__ __launch_bounds__(256) void stats_kernel(
    const float4* __restrict__ partials, float* __restrict__ coef)
{
    const int b = blockIdx.x;
    const int tid = threadIdx.x;
    __shared__ float sred[4];

    const float4 p0 = partials[b * SEQ + tid];
    const float4 p1 = partials[b * SEQ + tid + 256];
    float sm  = p0.x + p1.x;
    float sm2 = p0.y + p1.y;
    float st  = p0.z + p1.z;
    float st2 = p0.w + p1.w;
    sm  = blockReduceSum(sm,  sred);
    sm2 = blockReduceSum(sm2, sred);
    st  = blockReduceSum(st,  sred);
    st2 = blockReduceSum(st2, sred);

    if (tid == 0) {
        const float n = (float)SEQ * (float)SEQ;
        const float e_o = sqrtf(sm2) + 1e-4f;
        const float e_t = sqrtf(st2) + 1e-4f;
        const float gamma = fminf(fmaxf(e_o / e_t, 0.8f), 1.2f);
        const float o_mean = sm / n, t0m = st / n;
        const float o_var = fmaxf(sm2 / n - o_mean * o_mean, 0.f);
        const float o_std = sqrtf(fmaxf(o_var, 0.01f));
        const float t0var = fmaxf(st2 / n - t0m * t0m, 0.f);
        const float t_std = sqrtf(fmaxf(gamma * gamma * t0var, 0.01f));
        const float gdyn = fminf(fmaxf(o_std / t_std, 0.8f), 1.2f);
        const float c1 = gdyn * gamma;
        coef[b] = o_mean - c1 * t0m;   // c0
        coef[BATCH + b] = c1;          // c1
    }
}

// ---------------- residual + final clamp + softmax (in place) ------------
__global__ __launch_bounds__(256) void softmax_kernel(
    float* __restrict__ scores,            // [B,H,S,S] in -> attn out
    const float* __restrict__ t0,          // [B,S,S]
    const float* __restrict__ coef)        // c0[B], c1[B]
{
    const int r = blockIdx.x;              // (b*H+h)*S + i
    const int i = r & 511;
    const int bh = r >> 9;
    const int b = bh >> 3;
    const float c0 = coef[b], c1 = coef[BATCH + b];
    float* row = scores + (long)r * SEQ;
    const float* trow = t0 + ((long)b * SEQ + i) * SEQ;
    const int tid = threadIdx.x;
    __shared__ float sred[4];

    float v[2], lmax = -1e30f;
    #pragma unroll
    for (int u = 0; u < 2; u++) {
        const int j = tid + u * 256;
        float sv = row[j] + ALPHA * (c0 + c1 * trow[j]);
        sv = fminf(fmaxf(sv, -15.f), 15.f);
        v[u] = sv;
        lmax = fmaxf(lmax, sv);
    }
    const float rmax = blockReduceMax(lmax, sred);
    float ex[2], lsum = 0.f;
    #pragma unroll
    for (int u = 0; u < 2; u++) { ex[u] = expf(v[u] - rmax); lsum += ex[u]; }
    const float rsum = blockReduceSum(lsum, sred);
    const float inv = 1.f / rsum;
    #pragma unroll
    for (int u = 0; u < 2; u++) row[tid + u * 256] = ex[u] * inv;
}

// -------------------------------------------------------------------------
extern "C" void kernel_launch(void* const* d_in, const int* in_sizes, int n_in,
                              void* d_out, int out_size, void* d_ws, size_t ws_size,
                              hipStream_t stream) {
    const float* x  = (const float*)d_in[0];
    const float* wq = (const float*)d_in[1];
    const float* bq = (const float*)d_in[2];
    const float* wk = (const float*)d_in[3];
    const float* bk = (const float*)d_in[4];
    const float* wv = (const float*)d_in[5];
    const float* bv = (const float*)d_in[6];
    const float* wo = (const float*)d_in[7];
    const float* bo = (const float*)d_in[8];
    const float* w1 = (const float*)d_in[9];
    const float* b1 = (const float*)d_in[10];
    const float* w2 = (const float*)d_in[11];
    const float* b2 = (const float*)d_in[12];
    float* out = (float*)d_out;

    // workspace layout (floats); total ~50.3 MB
    float* ws       = (float*)d_ws;
    float* qbuf     = ws;                       // [B,H,S,DH]   1M
    float* kbuf     = qbuf + 1048576;           // [B,H,S,DH]   1M
    float* vT       = kbuf + 1048576;           // [B,H,DH,S]   1M
    float* scores   = vT + 1048576;             // [B,H,S,S]    8M
    float* t0       = scores + 8388608;         // [B,S,S]      1M
    float* partials = t0 + 1048576;             // 2048 float4 = 8192 floats
    float* coef     = partials + 8192;          // 8
    float* lutbuf   = coef + 8;                 // LUTN+1
    float* out_tmp  = qbuf;                     // reuse qbuf after attn@v

    const int MROWS = BATCH * SEQ;   // 2048
    const float scaling = 0.125f;    // DH^-0.5

    build_lut<<<dim3((LUTN + 256) / 256), dim3(256), 0, stream>>>(w1, b1, w2, b2, lutbuf);

    // QKV projections
    gemm_nt<<<dim3(EMB / BN, MROWS / BM, 1), dim3(256), 0, stream>>>(
        x, wq, bq, qbuf, MROWS, EMB, EMB, 0, 0, 0, scaling, 1);
    gemm_nt<<<dim3(EMB / BN, MROWS / BM, 1), dim3(256), 0, stream>>>(
        x, wk, bk, kbuf, MROWS, EMB, EMB, 0, 0, 0, 1.f, 1);
    gemm_nt<<<dim3(EMB / BN, MROWS / BM, 1), dim3(256), 0, stream>>>(
        x, wv, bv, vT, MROWS, EMB, EMB, 0, 0, 0, 1.f, 2);

    // scores = q @ k^T per (b,h), clamp
    gemm_nt<<<dim3(SEQ / BN, SEQ / BM, BATCH * NH), dim3(256), 0, stream>>>(
        qbuf, kbuf, nullptr, scores, SEQ, SEQ, DHD,
        (long)SEQ * DHD, (long)SEQ * DHD, (long)SEQ * SEQ, 1.f, 3);

    // autopoietic transform row kernel (LUT-based, atomic-free)
    transform_kernel<<<dim3(BATCH * SEQ), dim3(256), 0, stream>>>(
        scores, lutbuf, t0, (float4*)partials);

    stats_kernel<<<dim3(BATCH), dim3(256), 0, stream>>>((const float4*)partials, coef);

    // residual + clamp + softmax (scores -> attn in place)
    softmax_kernel<<<dim3(BATCH * NH * SEQ), dim3(256), 0, stream>>>(
        scores, t0, coef);

    // out_tmp[b,s,e] = attn @ v
    gemm_nt<<<dim3(DHD / BN, SEQ / BM, BATCH * NH), dim3(256), 0, stream>>>(
        scores, vT, nullptr, out_tmp, SEQ, DHD, SEQ,
        (long)SEQ * SEQ, (long)DHD * SEQ, 0, 1.f, 4);

    // final projection
    gemm_nt<<<dim3(EMB / BN, MROWS / BM, 1), dim3(256), 0, stream>>>(
        out_tmp, wo, bo, out, MROWS, EMB, EMB, 0, 0, 0, 1.f, 0);
}

// Round 4
// 231.005 us; speedup vs baseline: 1.7438x; 1.2736x over previous
//
#include <hip/hip_runtime.h>
#include <math.h>

// Problem constants (reference: B=4, S=512, E=512, H=8, DH=64, HID=128)
#define BATCH 4
#define SEQ   512
#define EMB   512
#define NH    8
#define DHD   64
#define HIDN  128
#define ALPHA 0.1f
#define EPSS  0.05f

// LUT for the pointwise conv-chain -> sigmoid function of `scaled`
#define LUTN  2048
#define XMIN  (-0.4f)
#define XSTEP (0.8f / LUTN)

typedef __attribute__((ext_vector_type(8))) short  bf16x8;
typedef __attribute__((ext_vector_type(4))) float  f32x4;
#define MFMA(a, b, c) __builtin_amdgcn_mfma_f32_16x16x32_bf16((a), (b), (c), 0, 0, 0)

__device__ __forceinline__ unsigned short f2bf(float f) {
    union { float f; unsigned u; } v; v.f = f;
    unsigned r = v.u + 0x7fffu + ((v.u >> 16) & 1u);   // RNE; inputs finite
    return (unsigned short)(r >> 16);
}
__device__ __forceinline__ float bf2f(unsigned short h) {
    union { unsigned u; float f; } v; v.u = ((unsigned)h) << 16;
    return v.f;
}

// ---------------- fp32 -> split bf16 (hi + lo correction) ----------------
__global__ __launch_bounds__(256) void split_bf16(
    const float* __restrict__ in, unsigned short* __restrict__ hi,
    unsigned short* __restrict__ lo, int n)
{
    const int i = blockIdx.x * 256 + threadIdx.x;
    if (i < n) {
        const float v = in[i];
        const unsigned short h = f2bf(v);
        hi[i] = h;
        lo[i] = f2bf(v - bf2f(h));
    }
}

// ---------------- fused QKV projection (split-bf16 MFMA) -----------------
// A = x split [2048, 512]; B = packed wq|wk|wv split [1536, 512].
// Block tile 64x64, 4 waves (2x2), each wave 32x32 = 2x2 MFMA tiles.
// q,k written as split bf16 [B,H,S,DH]; v written single bf16 [B,H,DH,S].
__global__ __launch_bounds__(256) void gemm_qkv(
    const unsigned short* __restrict__ xhi, const unsigned short* __restrict__ xlo,
    const unsigned short* __restrict__ wh,  const unsigned short* __restrict__ wl,
    const float* __restrict__ bq, const float* __restrict__ bk, const float* __restrict__ bv,
    unsigned short* __restrict__ qhi, unsigned short* __restrict__ qlo,
    unsigned short* __restrict__ khi, unsigned short* __restrict__ klo,
    unsigned short* __restrict__ vT)
{
    const int tid  = threadIdx.x;
    const int wave = tid >> 6, lane = tid & 63;
    const int quad = lane >> 4, r = lane & 15;
    const int m_base = blockIdx.y * 64 + (wave >> 1) * 32;
    const int n_base = blockIdx.x * 64 + (wave & 1) * 32;
    const int K = EMB;

    f32x4 acc[2][2] = {};
    const int koff0 = quad * 8;
    for (int k0 = 0; k0 < K; k0 += 32) {
        const int ko = k0 + koff0;
        bf16x8 ah[2], al[2], bh[2], bl[2];
        #pragma unroll
        for (int t = 0; t < 2; t++) {
            const long arow = (long)(m_base + t * 16 + r) * K + ko;
            ah[t] = *(const bf16x8*)(xhi + arow);
            al[t] = *(const bf16x8*)(xlo + arow);
            const long brow = (long)(n_base + t * 16 + r) * K + ko;
            bh[t] = *(const bf16x8*)(wh + brow);
            bl[t] = *(const bf16x8*)(wl + brow);
        }
        #pragma unroll
        for (int i = 0; i < 2; i++)
            #pragma unroll
            for (int j = 0; j < 2; j++) {
                acc[i][j] = MFMA(ah[i], bh[j], acc[i][j]);
                acc[i][j] = MFMA(al[i], bh[j], acc[i][j]);
                acc[i][j] = MFMA(ah[i], bl[j], acc[i][j]);
            }
    }

    #pragma unroll
    for (int i = 0; i < 2; i++) {
      #pragma unroll
      for (int j = 0; j < 2; j++) {
        #pragma unroll
        for (int g = 0; g < 4; g++) {
            const int m = m_base + i * 16 + quad * 4 + g;
            const int n = n_base + j * 16 + r;
            const int which = n >> 9, n2 = n & 511;
            const int b = m >> 9, s = m & 511, h = n2 >> 6, d = n2 & 63;
            float val = acc[i][j][g];
            if (which == 0) {
                val = (val + bq[n2]) * 0.125f;   // DH^-0.5
                const long idx = (((long)(b * NH + h)) * SEQ + s) * DHD + d;
                const unsigned short hv = f2bf(val);
                qhi[idx] = hv; qlo[idx] = f2bf(val - bf2f(hv));
            } else if (which == 1) {
                val += bk[n2];
                const long idx = (((long)(b * NH + h)) * SEQ + s) * DHD + d;
                const unsigned short hv = f2bf(val);
                khi[idx] = hv; klo[idx] = f2bf(val - bf2f(hv));
            } else {
                val += bv[n2];
                vT[(((long)(b * NH + h)) * DHD + d) * SEQ + s] = f2bf(val);
            }
        }
      }
    }
}

// ---------------- generic NT MFMA GEMM (optional split operands) ---------
// C[m,n] = sum_k A[m,k]*B[n,k]. Block 64x64, wave 32x32.
// mode 0: scores fp32 + clamp(+-15), C += z*strideC
// mode 1: attn@v -> out_tmp bf16 [b, m, h*64+n], z=(b*NH+h)
// mode 2: proj fp32 + bias, [m*N+n]
__global__ __launch_bounds__(256) void gemm_mfma(
    const unsigned short* __restrict__ Ahi, const unsigned short* __restrict__ Alo,
    const unsigned short* __restrict__ Bhi, const unsigned short* __restrict__ Blo,
    const float* __restrict__ bias, void* __restrict__ Cout,
    int N, int K, long strideA, long strideB, long strideC, int mode)
{
    const int z = blockIdx.z;
    Ahi += (long)z * strideA;
    Bhi += (long)z * strideB;
    const bool sa = (Alo != nullptr), sb = (Blo != nullptr);
    if (sa) Alo += (long)z * strideA;
    if (sb) Blo += (long)z * strideB;

    const int tid  = threadIdx.x;
    const int wave = tid >> 6, lane = tid & 63;
    const int quad = lane >> 4, r = lane & 15;
    const int m_base = blockIdx.y * 64 + (wave >> 1) * 32;
    const int n_base = blockIdx.x * 64 + (wave & 1) * 32;

    f32x4 acc[2][2] = {};
    const int koff0 = quad * 8;
    for (int k0 = 0; k0 < K; k0 += 32) {
        const int ko = k0 + koff0;
        bf16x8 ah[2], al[2], bh[2], bl[2];
        #pragma unroll
        for (int t = 0; t < 2; t++) {
            const long arow = (long)(m_base + t * 16 + r) * K + ko;
            ah[t] = *(const bf16x8*)(Ahi + arow);
            if (sa) al[t] = *(const bf16x8*)(Alo + arow);
            const long brow = (long)(n_base + t * 16 + r) * K + ko;
            bh[t] = *(const bf16x8*)(Bhi + brow);
            if (sb) bl[t] = *(const bf16x8*)(Blo + brow);
        }
        #pragma unroll
        for (int i = 0; i < 2; i++)
            #pragma unroll
            for (int j = 0; j < 2; j++) {
                acc[i][j] = MFMA(ah[i], bh[j], acc[i][j]);
                if (sa) acc[i][j] = MFMA(al[i], bh[j], acc[i][j]);
                if (sb) acc[i][j] = MFMA(ah[i], bl[j], acc[i][j]);
            }
    }

    #pragma unroll
    for (int i = 0; i < 2; i++) {
      #pragma unroll
      for (int j = 0; j < 2; j++) {
        #pragma unroll
        for (int g = 0; g < 4; g++) {
            const int m = m_base + i * 16 + quad * 4 + g;
            const int n = n_base + j * 16 + r;
            float val = acc[i][j][g];
            if (mode == 0) {
                val = fminf(fmaxf(val, -15.f), 15.f);
                ((float*)Cout)[z * strideC + (long)m * N + n] = val;
            } else if (mode == 1) {
                const int b = z >> 3, h = z & 7;
                ((unsigned short*)Cout)[((long)(b * SEQ + m)) * EMB + h * DHD + n] = f2bf(val);
            } else {
                val += bias[n];
                ((float*)Cout)[(long)m * N + n] = val;
            }
        }
      }
    }
}

// ---------------- block reduction helpers (blockDim=256, 4 waves) --------
__device__ __forceinline__ float blockReduceMax(float v, float* sred) {
    #pragma unroll
    for (int o = 32; o > 0; o >>= 1) v = fmaxf(v, __shfl_down(v, o));
    __syncthreads();
    if ((threadIdx.x & 63) == 0) sred[threadIdx.x >> 6] = v;
    __syncthreads();
    return fmaxf(fmaxf(sred[0], sred[1]), fmaxf(sred[2], sred[3]));
}
__device__ __forceinline__ float blockReduceSum(float v, float* sred) {
    #pragma unroll
    for (int o = 32; o > 0; o >>= 1) v += __shfl_down(v, o);
    __syncthreads();
    if ((threadIdx.x & 63) == 0) sred[threadIdx.x >> 6] = v;
    __syncthreads();
    return (sred[0] + sred[1]) + (sred[2] + sred[3]);
}

// ---------------- build the pointwise-function LUT -----------------------
__global__ void build_lut(
    const float* __restrict__ w1, const float* __restrict__ b1,
    const float* __restrict__ w2, const float* __restrict__ b2,
    float* __restrict__ lut)
{
    const int i = blockIdx.x * blockDim.x + threadIdx.x;
    if (i > LUTN) return;
    const float x = XMIN + i * XSTEP;
    float a = 0.f;
    for (int h = 0; h < HIDN; h++) {
        float hv = x * w1[h] + b1[h];
        hv = fminf(fmaxf(hv, -5.f), 5.f);
        hv = fmaxf(hv, 0.f);
        a += hv * w2[h];
    }
    a += b2[0];
    a = fminf(fmaxf(a, -5.f), 5.f);
    const float taylor = fminf(fmaxf(1.f + 2.5f * a, 0.5f), 1.5f);
    lut[i] = 1.f / (1.f + expf(-taylor));
}

// ---------------- transform kernel: one block per (b,i) row --------------
__global__ __launch_bounds__(256) void transform_kernel(
    const float* __restrict__ scores,      // [B,H,S,S] (clamped)
    const float* __restrict__ lut,         // [LUTN+1]
    float* __restrict__ t0,                // [B,S,S]
    float4* __restrict__ partials)         // [B*S] float4 slots
{
    const int r = blockIdx.x;
    const int b = r >> 9, i = r & 511;
    const int tid = threadIdx.x;

    __shared__ float slut[LUTN + 1];
    __shared__ float sred[4];

    for (int u = tid; u <= LUTN; u += 256) slut[u] = lut[u];

    const float* base = scores + (((long)(b * NH)) * SEQ + i) * SEQ;

    float mv[2], sigv[2], mclip[2];
    float lmax = -1e30f;
    __syncthreads();
    #pragma unroll
    for (int u = 0; u < 2; u++) {
        const int j = tid + u * 256;
        float s = 0.f;
        #pragma unroll
        for (int h = 0; h < NH; h++) s += base[(long)h * SEQ * SEQ + j];
        const float m = s * (1.0f / NH);
        mv[u] = m;
        const float x = fminf(fmaxf(m, -8.f), 8.f) * EPSS;
        float t = (x - XMIN) * (1.0f / XSTEP);
        int idx = (int)t;
        idx = idx < 0 ? 0 : (idx > LUTN - 1 ? LUTN - 1 : idx);
        const float frac = t - (float)idx;
        const float l0 = slut[idx], l1 = slut[idx + 1];
        sigv[u] = l0 + frac * (l1 - l0);
        const float mc = fminf(fmaxf(m, -10.f), 10.f);
        mclip[u] = mc;
        lmax = fmaxf(lmax, mc);
    }

    const float rmax = blockReduceMax(lmax, sred);
    float ex[2], lsum = 0.f;
    #pragma unroll
    for (int u = 0; u < 2; u++) { ex[u] = expf(mclip[u] - rmax); lsum += ex[u]; }
    const float rsum = blockReduceSum(lsum, sred);
    const float inv = 1.f / rsum;

    float hent[2], lmax2 = -1e30f;
    #pragma unroll
    for (int u = 0; u < 2; u++) {
        const float p = ex[u] * inv;
        const float he = -p * logf(p + 1e-6f);
        hent[u] = 3.f * he;
        lmax2 = fmaxf(lmax2, hent[u]);
    }
    const float rmax2 = blockReduceMax(lmax2, sred);
    float ex2[2], lsum2 = 0.f;
    #pragma unroll
    for (int u = 0; u < 2; u++) { ex2[u] = expf(hent[u] - rmax2); lsum2 += ex2[u]; }
    const float rsum2 = blockReduceSum(lsum2, sred);
    const float inv2 = 1.f / rsum2;

    float s_m = 0.f, s_m2 = 0.f, s_t = 0.f, s_t2 = 0.f;
    #pragma unroll
    for (int u = 0; u < 2; u++) {
        const int j = tid + u * 256;
        const float Fm = ex2[u] * inv2;
        const float tv = sigv[u] * Fm;
        t0[((long)b * SEQ + i) * SEQ + j] = tv;
        s_m += mv[u]; s_m2 += mv[u] * mv[u];
        s_t += tv;    s_t2 += tv * tv;
    }
    s_m  = blockReduceSum(s_m,  sred);
    s_m2 = blockReduceSum(s_m2, sred);
    s_t  = blockReduceSum(s_t,  sred);
    s_t2 = blockReduceSum(s_t2, sred);
    if (tid == 0) {
        partials[r] = make_float4(s_m, s_m2, s_t, s_t2);
    }
}

// ---------------- per-batch stats reduction -> c0,c1 ---------------------
__global__ __launch_bounds__(256) void stats_kernel(
    const float4* __restrict__ partials, float* __restrict__ coef)
{
    const int b = blockIdx.x;
    const int tid = threadIdx.x;
    __shared__ float sred[4];

    const float4 p0 = partials[b * SEQ + tid];
    const float4 p1 = partials[b * SEQ + tid + 256];
    float sm  = p0.x + p1.x;
    float sm2 = p0.y + p1.y;
    float st  = p0.z + p1.z;
    float st2 = p0.w + p1.w;
    sm  = blockReduceSum(sm,  sred);
    sm2 = blockReduceSum(sm2, sred);
    st  = blockReduceSum(st,  sred);
    st2 = blockReduceSum(st2, sred);

    if (tid == 0) {
        const float n = (float)SEQ * (float)SEQ;
        const float e_o = sqrtf(sm2) + 1e-4f;
        const float e_t = sqrtf(st2) + 1e-4f;
        const float gamma = fminf(fmaxf(e_o / e_t, 0.8f), 1.2f);
        const float o_mean = sm / n, t0m = st / n;
        const float o_var = fmaxf(sm2 / n - o_mean * o_mean, 0.f);
        const float o_std = sqrtf(fmaxf(o_var, 0.01f));
        const float t0var = fmaxf(st2 / n - t0m * t0m, 0.f);
        const float t_std = sqrtf(fmaxf(gamma * gamma * t0var, 0.01f));
        const float gdyn = fminf(fmaxf(o_std / t_std, 0.8f), 1.2f);
        const float c1 = gdyn * gamma;
        coef[b] = o_mean - c1 * t0m;   // c0
        coef[BATCH + b] = c1;          // c1
    }
}

// ---------------- residual + final clamp + softmax -> bf16 attn ----------
__global__ __launch_bounds__(256) void softmax_kernel(
    const float* __restrict__ scores,      // [B,H,S,S]
    const float* __restrict__ t0,          // [B,S,S]
    const float* __restrict__ coef,        // c0[B], c1[B]
    unsigned short* __restrict__ attn)     // [B,H,S,S] bf16
{
    const int r = blockIdx.x;              // (b*H+h)*S + i
    const int i = r & 511;
    const int bh = r >> 9;
    const int b = bh >> 3;
    const float c0 = coef[b], c1 = coef[BATCH + b];
    const float* row = scores + (long)r * SEQ;
    const float* trow = t0 + ((long)b * SEQ + i) * SEQ;
    const int tid = threadIdx.x;
    __shared__ float sred[4];

    float v[2], lmax = -1e30f;
    #pragma unroll
    for (int u = 0; u < 2; u++) {
        const int j = tid + u * 256;
        float sv = row[j] + ALPHA * (c0 + c1 * trow[j]);
        sv = fminf(fmaxf(sv, -15.f), 15.f);
        v[u] = sv;
        lmax = fmaxf(lmax, sv);
    }
    const float rmax = blockReduceMax(lmax, sred);
    float ex[2], lsum = 0.f;
    #pragma unroll
    for (int u = 0; u < 2; u++) { ex[u] = expf(v[u] - rmax); lsum += ex[u]; }
    const float rsum = blockReduceSum(lsum, sred);
    const float inv = 1.f / rsum;
    #pragma unroll
    for (int u = 0; u < 2; u++)
        attn[(long)r * SEQ + tid + u * 256] = f2bf(ex[u] * inv);
}

// -------------------------------------------------------------------------
extern "C" void kernel_launch(void* const* d_in, const int* in_sizes, int n_in,
                              void* d_out, int out_size, void* d_ws, size_t ws_size,
                              hipStream_t stream) {
    const float* x  = (const float*)d_in[0];
    const float* wq = (const float*)d_in[1];
    const float* bq = (const float*)d_in[2];
    const float* wk = (const float*)d_in[3];
    const float* bk = (const float*)d_in[4];
    const float* wv = (const float*)d_in[5];
    const float* bv = (const float*)d_in[6];
    const float* wo = (const float*)d_in[7];
    const float* bo = (const float*)d_in[8];
    const float* w1 = (const float*)d_in[9];
    const float* b1 = (const float*)d_in[10];
    const float* w2 = (const float*)d_in[11];
    const float* b2 = (const float*)d_in[12];
    float* out = (float*)d_out;

    // ---- workspace layout ----
    char* wsb = (char*)d_ws;
    float*  scores   = (float*)wsb;                    // 32 MB  [B,H,S,S]
    float*  t0       = scores + 8388608;               // 4 MB   [B,S,S]
    float4* partials = (float4*)(t0 + 1048576);        // 32 KB
    float*  coef     = (float*)(partials + 2048);      // 8
    float*  lutbuf   = coef + 8;                       // LUTN+1
    unsigned short* u16 = (unsigned short*)(wsb + (40u << 20));
    unsigned short* xhi   = u16;                       // 1048576
    unsigned short* xlo   = xhi + 1048576;
    unsigned short* wqkvh = xlo + 1048576;             // 786432 (wq|wk|wv)
    unsigned short* wqkvl = wqkvh + 786432;
    unsigned short* woh   = wqkvl + 786432;            // 262144
    unsigned short* wol   = woh + 262144;              // written, unused
    unsigned short* qhi   = wol + 262144;              // 1048576 [B,H,S,DH]
    unsigned short* qlo   = qhi + 1048576;
    unsigned short* khi   = qlo + 1048576;
    unsigned short* klo   = khi + 1048576;
    unsigned short* vT    = klo + 1048576;             // [B,H,DH,S]
    unsigned short* attn  = vT + 1048576;              // 8388608 [B,H,S,S]
    unsigned short* otmp  = attn + 8388608;            // 1048576 [B,S,E]

    build_lut<<<dim3((LUTN + 256) / 256), dim3(256), 0, stream>>>(w1, b1, w2, b2, lutbuf);

    // split fp32 -> bf16 hi/lo
    split_bf16<<<dim3(4096), dim3(256), 0, stream>>>(x,  xhi, xlo, 1048576);
    split_bf16<<<dim3(1024), dim3(256), 0, stream>>>(wq, wqkvh,          wqkvl,          262144);
    split_bf16<<<dim3(1024), dim3(256), 0, stream>>>(wk, wqkvh + 262144, wqkvl + 262144, 262144);
    split_bf16<<<dim3(1024), dim3(256), 0, stream>>>(wv, wqkvh + 524288, wqkvl + 524288, 262144);
    split_bf16<<<dim3(1024), dim3(256), 0, stream>>>(wo, woh, wol, 262144);

    // fused QKV projection (split x * split w, 3-MFMA)
    gemm_qkv<<<dim3(24, 32), dim3(256), 0, stream>>>(
        xhi, xlo, wqkvh, wqkvl, bq, bk, bv, qhi, qlo, khi, klo, vT);

    // scores = q @ k^T per (b,h) (split q * split k), clamp
    gemm_mfma<<<dim3(8, 8, 32), dim3(256), 0, stream>>>(
        qhi, qlo, khi, klo, nullptr, scores,
        SEQ, DHD, (long)SEQ * DHD, (long)SEQ * DHD, (long)SEQ * SEQ, 0);

    // autopoietic transform (LUT-based, atomic-free)
    transform_kernel<<<dim3(BATCH * SEQ), dim3(256), 0, stream>>>(
        scores, lutbuf, t0, partials);

    stats_kernel<<<dim3(BATCH), dim3(256), 0, stream>>>(partials, coef);

    // residual + clamp + softmax -> bf16 attn
    softmax_kernel<<<dim3(BATCH * NH * SEQ), dim3(256), 0, stream>>>(
        scores, t0, coef, attn);

    // out_tmp = attn @ v  (single bf16)
    gemm_mfma<<<dim3(1, 8, 32), dim3(256), 0, stream>>>(
        attn, nullptr, vT, nullptr, nullptr, otmp,
        DHD, SEQ, (long)SEQ * SEQ, (long)DHD * SEQ, 0, 1);

    // out = out_tmp @ wo^T + bo  (single bf16, fp32 out)
    gemm_mfma<<<dim3(8, 32, 1), dim3(256), 0, stream>>>(
        otmp, nullptr, woh, nullptr, bo, out,
        EMB, EMB, 0, 0, 0, 2);
}

// Round 5
// 200.272 us; speedup vs baseline: 2.0114x; 1.1535x over previous
//
#include <hip/hip_runtime.h>
#include <math.h>

// Problem constants (reference: B=4, S=512, E=512, H=8, DH=64, HID=128)
#define BATCH 4
#define SEQ   512
#define EMB   512
#define NH    8
#define DHD   64
#define HIDN  128
#define ALPHA 0.1f
#define EPSS  0.05f

// LUT for the pointwise conv-chain -> sigmoid function of `scaled`
#define LUTN  2048
#define XMIN  (-0.4f)
#define XSTEP (0.8f / LUTN)

typedef __attribute__((ext_vector_type(8))) short  bf16x8;
typedef __attribute__((ext_vector_type(4))) float  f32x4;
#define MFMA(a, b, c) __builtin_amdgcn_mfma_f32_16x16x32_bf16((a), (b), (c), 0, 0, 0)

__device__ __forceinline__ unsigned short f2bf(float f) {
    union { float f; unsigned u; } v; v.f = f;
    unsigned r = v.u + 0x7fffu + ((v.u >> 16) & 1u);   // RNE; inputs finite
    return (unsigned short)(r >> 16);
}
__device__ __forceinline__ float bf2f(unsigned short h) {
    union { unsigned u; float f; } v; v.u = ((unsigned)h) << 16;
    return v.f;
}

// ---------------- MFMA K-pipeline (register ring prefetch) ---------------
// Wave computes a 32x32 tile as 2x2 MFMA 16x16x32 tiles. K = STEPS*32,
// fully unrolled; loads for step s+RING-1 issue before MFMAs of step s.
// SPLIT: A,B have hi+lo bf16 parts -> 3 MFMAs/tile (hi*hi+lo*hi+hi*lo).
template<int STEPS, bool SPLIT, int RING>
__device__ __forceinline__ void mfma_pipe(
    const unsigned short* __restrict__ Ahi, const unsigned short* __restrict__ Alo,
    const unsigned short* __restrict__ Bhi, const unsigned short* __restrict__ Blo,
    int m_base, int n_base, int quad, int r, f32x4 acc[2][2])
{
    const int K = STEPS * 32;
    const long a0 = (long)(m_base + r) * K + quad * 8;
    const long a1 = a0 + 16 * K;
    const long b0 = (long)(n_base + r) * K + quad * 8;
    const long b1 = b0 + 16 * K;

    bf16x8 ah[RING][2], bh[RING][2], al[RING][2], bl[RING][2];

#define PIPE_LD(st, s) do {                                      \
        ah[st][0] = *(const bf16x8*)(Ahi + a0 + (s) * 32);       \
        ah[st][1] = *(const bf16x8*)(Ahi + a1 + (s) * 32);       \
        bh[st][0] = *(const bf16x8*)(Bhi + b0 + (s) * 32);       \
        bh[st][1] = *(const bf16x8*)(Bhi + b1 + (s) * 32);       \
        if (SPLIT) {                                             \
            al[st][0] = *(const bf16x8*)(Alo + a0 + (s) * 32);   \
            al[st][1] = *(const bf16x8*)(Alo + a1 + (s) * 32);   \
            bl[st][0] = *(const bf16x8*)(Blo + b0 + (s) * 32);   \
            bl[st][1] = *(const bf16x8*)(Blo + b1 + (s) * 32);   \
        } } while (0)

    constexpr int PRE = (RING - 1 < STEPS) ? RING - 1 : STEPS;
    #pragma unroll
    for (int s = 0; s < PRE; s++) PIPE_LD(s, s);
    #pragma unroll
    for (int s = 0; s < STEPS; s++) {
        if (s + RING - 1 < STEPS) PIPE_LD((s + RING - 1) % RING, s + RING - 1);
        const int c = s % RING;
        #pragma unroll
        for (int i = 0; i < 2; i++)
            #pragma unroll
            for (int j = 0; j < 2; j++) {
                acc[i][j] = MFMA(ah[c][i], bh[c][j], acc[i][j]);
                if (SPLIT) {
                    acc[i][j] = MFMA(al[c][i], bh[c][j], acc[i][j]);
                    acc[i][j] = MFMA(ah[c][i], bl[c][j], acc[i][j]);
                }
            }
    }
#undef PIPE_LD
}

// ---------------- fused QKV projection (split-bf16 MFMA) -----------------
// A = x split [2048,512]; B = packed wq|wk|wv split [1536,512]. Grid 24x32.
__global__ __launch_bounds__(256, 3) void gemm_qkv(
    const unsigned short* __restrict__ xhi, const unsigned short* __restrict__ xlo,
    const unsigned short* __restrict__ wh,  const unsigned short* __restrict__ wl,
    const float* __restrict__ bq, const float* __restrict__ bk, const float* __restrict__ bv,
    unsigned short* __restrict__ qhi, unsigned short* __restrict__ qlo,
    unsigned short* __restrict__ khi, unsigned short* __restrict__ klo,
    unsigned short* __restrict__ vT)
{
    const int tid  = threadIdx.x;
    const int wave = tid >> 6, lane = tid & 63;
    const int quad = lane >> 4, r = lane & 15;
    const int m_base = blockIdx.y * 64 + (wave >> 1) * 32;
    const int n_base = blockIdx.x * 64 + (wave & 1) * 32;

    f32x4 acc[2][2] = {};
    mfma_pipe<16, true, 3>(xhi, xlo, wh, wl, m_base, n_base, quad, r, acc);

    #pragma unroll
    for (int i = 0; i < 2; i++) {
      #pragma unroll
      for (int j = 0; j < 2; j++) {
        #pragma unroll
        for (int g = 0; g < 4; g++) {
            const int m = m_base + i * 16 + quad * 4 + g;
            const int n = n_base + j * 16 + r;
            const int which = n >> 9, n2 = n & 511;
            const int b = m >> 9, s = m & 511, h = n2 >> 6, d = n2 & 63;
            float val = acc[i][j][g];
            if (which == 0) {
                val = (val + bq[n2]) * 0.125f;   // DH^-0.5
                const long idx = (((long)(b * NH + h)) * SEQ + s) * DHD + d;
                const unsigned short hv = f2bf(val);
                qhi[idx] = hv; qlo[idx] = f2bf(val - bf2f(hv));
            } else if (which == 1) {
                val += bk[n2];
                const long idx = (((long)(b * NH + h)) * SEQ + s) * DHD + d;
                const unsigned short hv = f2bf(val);
                khi[idx] = hv; klo[idx] = f2bf(val - bf2f(hv));
            } else {
                val += bv[n2];
                vT[(((long)(b * NH + h)) * DHD + d) * SEQ + s] = f2bf(val);
            }
        }
      }
    }
}

// ---------------- scores = q @ k^T per (b,h), split, clamp ---------------
// Grid (8, 8, 32).
__global__ __launch_bounds__(256, 4) void gemm_scores(
    const unsigned short* __restrict__ qhi, const unsigned short* __restrict__ qlo,
    const unsigned short* __restrict__ khi, const unsigned short* __restrict__ klo,
    float* __restrict__ scores)
{
    const int z = blockIdx.z;
    const long zo = (long)z * SEQ * DHD;
    const int tid  = threadIdx.x;
    const int wave = tid >> 6, lane = tid & 63;
    const int quad = lane >> 4, r = lane & 15;
    const int m_base = blockIdx.y * 64 + (wave >> 1) * 32;
    const int n_base = blockIdx.x * 64 + (wave & 1) * 32;

    f32x4 acc[2][2] = {};
    mfma_pipe<2, true, 2>(qhi + zo, qlo + zo, khi + zo, klo + zo,
                          m_base, n_base, quad, r, acc);

    float* C = scores + (long)z * SEQ * SEQ;
    #pragma unroll
    for (int i = 0; i < 2; i++)
      #pragma unroll
      for (int j = 0; j < 2; j++)
        #pragma unroll
        for (int g = 0; g < 4; g++) {
            const int m = m_base + i * 16 + quad * 4 + g;
            const int n = n_base + j * 16 + r;
            float val = acc[i][j][g];
            val = fminf(fmaxf(val, -15.f), 15.f);
            C[(long)m * SEQ + n] = val;
        }
}

// ---------------- out_tmp = attn @ v (single bf16) -----------------------
// Grid (1, 8, 32); z = b*NH + h.
__global__ __launch_bounds__(256, 3) void gemm_attnv(
    const unsigned short* __restrict__ attn, const unsigned short* __restrict__ vT,
    unsigned short* __restrict__ otmp)
{
    const int z = blockIdx.z;
    const int tid  = threadIdx.x;
    const int wave = tid >> 6, lane = tid & 63;
    const int quad = lane >> 4, r = lane & 15;
    const int m_base = blockIdx.y * 64 + (wave >> 1) * 32;
    const int n_base = (wave & 1) * 32;

    f32x4 acc[2][2] = {};
    mfma_pipe<16, false, 4>(attn + (long)z * SEQ * SEQ, nullptr,
                            vT + (long)z * DHD * SEQ, nullptr,
                            m_base, n_base, quad, r, acc);

    const int b = z >> 3, h = z & 7;
    #pragma unroll
    for (int i = 0; i < 2; i++)
      #pragma unroll
      for (int j = 0; j < 2; j++)
        #pragma unroll
        for (int g = 0; g < 4; g++) {
            const int m = m_base + i * 16 + quad * 4 + g;
            const int n = n_base + j * 16 + r;
            otmp[((long)(b * SEQ + m)) * EMB + h * DHD + n] = f2bf(acc[i][j][g]);
        }
}

// ---------------- out = out_tmp @ wo^T + bo (single bf16, fp32 out) ------
// Grid (8, 32).
__global__ __launch_bounds__(256, 3) void gemm_proj(
    const unsigned short* __restrict__ otmp, const unsigned short* __restrict__ woh,
    const float* __restrict__ bo, float* __restrict__ out)
{
    const int tid  = threadIdx.x;
    const int wave = tid >> 6, lane = tid & 63;
    const int quad = lane >> 4, r = lane & 15;
    const int m_base = blockIdx.y * 64 + (wave >> 1) * 32;
    const int n_base = blockIdx.x * 64 + (wave & 1) * 32;

    f32x4 acc[2][2] = {};
    mfma_pipe<16, false, 4>(otmp, nullptr, woh, nullptr,
                            m_base, n_base, quad, r, acc);

    #pragma unroll
    for (int i = 0; i < 2; i++)
      #pragma unroll
      for (int j = 0; j < 2; j++)
        #pragma unroll
        for (int g = 0; g < 4; g++) {
            const int m = m_base + i * 16 + quad * 4 + g;
            const int n = n_base + j * 16 + r;
            out[(long)m * EMB + n] = acc[i][j][g] + bo[n];
        }
}

// ---------------- block reduction helpers (blockDim=256, 4 waves) --------
__device__ __forceinline__ float blockReduceMax(float v, float* sred) {
    #pragma unroll
    for (int o = 32; o > 0; o >>= 1) v = fmaxf(v, __shfl_down(v, o));
    __syncthreads();
    if ((threadIdx.x & 63) == 0) sred[threadIdx.x >> 6] = v;
    __syncthreads();
    return fmaxf(fmaxf(sred[0], sred[1]), fmaxf(sred[2], sred[3]));
}
__device__ __forceinline__ float blockReduceSum(float v, float* sred) {
    #pragma unroll
    for (int o = 32; o > 0; o >>= 1) v += __shfl_down(v, o);
    __syncthreads();
    if ((threadIdx.x & 63) == 0) sred[threadIdx.x >> 6] = v;
    __syncthreads();
    return (sred[0] + sred[1]) + (sred[2] + sred[3]);
}

// ---------------- fused prep: LUT build + all fp32->bf16 splits ----------
// blocks [0,9): LUT; blocks [9, 9+8192): splits of x|wq|wk|wv|wo.
__global__ __launch_bounds__(256) void prep_kernel(
    const float* __restrict__ x,
    const float* __restrict__ wq, const float* __restrict__ wk,
    const float* __restrict__ wv, const float* __restrict__ wo,
    const float* __restrict__ w1, const float* __restrict__ b1,
    const float* __restrict__ w2, const float* __restrict__ b2,
    unsigned short* __restrict__ xhi, unsigned short* __restrict__ xlo,
    unsigned short* __restrict__ wqkvh, unsigned short* __restrict__ wqkvl,
    unsigned short* __restrict__ woh, float* __restrict__ lut)
{
    const int blk = blockIdx.x;
    if (blk < 9) {
        const int i = blk * 256 + threadIdx.x;
        if (i > LUTN) return;
        const float xv = XMIN + i * XSTEP;
        float a = 0.f;
        for (int h = 0; h < HIDN; h++) {
            float hv = xv * w1[h] + b1[h];
            hv = fminf(fmaxf(hv, -5.f), 5.f);
            hv = fmaxf(hv, 0.f);
            a += hv * w2[h];
        }
        a += b2[0];
        a = fminf(fmaxf(a, -5.f), 5.f);
        const float taylor = fminf(fmaxf(1.f + 2.5f * a, 0.5f), 1.5f);
        lut[i] = 1.f / (1.f + expf(-taylor));
        return;
    }
    const int i = (blk - 9) * 256 + threadIdx.x;  // 0 .. 2097151
    if (i < 1048576) {
        const float v = x[i];
        const unsigned short h = f2bf(v);
        xhi[i] = h; xlo[i] = f2bf(v - bf2f(h));
    } else if (i < 1835008) {
        const int j = i - 1048576;                // 0 .. 786431 over wq|wk|wv
        const float v = (j < 262144) ? wq[j] : (j < 524288 ? wk[j - 262144] : wv[j - 524288]);
        const unsigned short h = f2bf(v);
        wqkvh[j] = h; wqkvl[j] = f2bf(v - bf2f(h));
    } else {
        const int j = i - 1835008;
        woh[j] = f2bf(wo[j]);
    }
}

// ---------------- transform kernel: one block per (b,i) row --------------
__global__ __launch_bounds__(256) void transform_kernel(
    const float* __restrict__ scores,      // [B,H,S,S] (clamped)
    const float* __restrict__ lut,         // [LUTN+1]
    float* __restrict__ t0,                // [B,S,S]
    float4* __restrict__ partials)         // [B*S] float4 slots
{
    const int r = blockIdx.x;
    const int b = r >> 9, i = r & 511;
    const int tid = threadIdx.x;

    __shared__ float slut[LUTN + 1];
    __shared__ float sred[4];

    for (int u = tid; u <= LUTN; u += 256) slut[u] = lut[u];

    const float* base = scores + (((long)(b * NH)) * SEQ + i) * SEQ;

    float mv[2], sigv[2], mclip[2];
    float lmax = -1e30f;
    __syncthreads();
    #pragma unroll
    for (int u = 0; u < 2; u++) {
        const int j = tid + u * 256;
        float s = 0.f;
        #pragma unroll
        for (int h = 0; h < NH; h++) s += base[(long)h * SEQ * SEQ + j];
        const float m = s * (1.0f / NH);
        mv[u] = m;
        const float x = fminf(fmaxf(m, -8.f), 8.f) * EPSS;
        float t = (x - XMIN) * (1.0f / XSTEP);
        int idx = (int)t;
        idx = idx < 0 ? 0 : (idx > LUTN - 1 ? LUTN - 1 : idx);
        const float frac = t - (float)idx;
        const float l0 = slut[idx], l1 = slut[idx + 1];
        sigv[u] = l0 + frac * (l1 - l0);
        const float mc = fminf(fmaxf(m, -10.f), 10.f);
        mclip[u] = mc;
        lmax = fmaxf(lmax, mc);
    }

    const float rmax = blockReduceMax(lmax, sred);
    float ex[2], lsum = 0.f;
    #pragma unroll
    for (int u = 0; u < 2; u++) { ex[u] = expf(mclip[u] - rmax); lsum += ex[u]; }
    const float rsum = blockReduceSum(lsum, sred);
    const float inv = 1.f / rsum;

    float hent[2], lmax2 = -1e30f;
    #pragma unroll
    for (int u = 0; u < 2; u++) {
        const float p = ex[u] * inv;
        const float he = -p * logf(p + 1e-6f);
        hent[u] = 3.f * he;
        lmax2 = fmaxf(lmax2, hent[u]);
    }
    const float rmax2 = blockReduceMax(lmax2, sred);
    float ex2[2], lsum2 = 0.f;
    #pragma unroll
    for (int u = 0; u < 2; u++) { ex2[u] = expf(hent[u] - rmax2); lsum2 += ex2[u]; }
    const float rsum2 = blockReduceSum(lsum2, sred);
    const float inv2 = 1.f / rsum2;

    float s_m = 0.f, s_m2 = 0.f, s_t = 0.f, s_t2 = 0.f;
    #pragma unroll
    for (int u = 0; u < 2; u++) {
        const int j = tid + u * 256;
        const float Fm = ex2[u] * inv2;
        const float tv = sigv[u] * Fm;
        t0[((long)b * SEQ + i) * SEQ + j] = tv;
        s_m += mv[u]; s_m2 += mv[u] * mv[u];
        s_t += tv;    s_t2 += tv * tv;
    }
    s_m  = blockReduceSum(s_m,  sred);
    s_m2 = blockReduceSum(s_m2, sred);
    s_t  = blockReduceSum(s_t,  sred);
    s_t2 = blockReduceSum(s_t2, sred);
    if (tid == 0) {
        partials[r] = make_float4(s_m, s_m2, s_t, s_t2);
    }
}

// ---------------- per-batch stats reduction -> c0,c1 ---------------------
__global__ __launch_bounds__(256) void stats_kernel(
    const float4* __restrict__ partials, float* __restrict__ coef)
{
    const int b = blockIdx.x;
    const int tid = threadIdx.x;
    __shared__ float sred[4];

    const float4 p0 = partials[b * SEQ + tid];
    const float4 p1 = partials[b * SEQ + tid + 256];
    float sm  = p0.x + p1.x;
    float sm2 = p0.y + p1.y;
    float st  = p0.z + p1.z;
    float st2 = p0.w + p1.w;
    sm  = blockReduceSum(sm,  sred);
    sm2 = blockReduceSum(sm2, sred);
    st  = blockReduceSum(st,  sred);
    st2 = blockReduceSum(st2, sred);

    if (tid == 0) {
        const float n = (float)SEQ * (float)SEQ;
        const float e_o = sqrtf(sm2) + 1e-4f;
        const float e_t = sqrtf(st2) + 1e-4f;
        const float gamma = fminf(fmaxf(e_o / e_t, 0.8f), 1.2f);
        const float o_mean = sm / n, t0m = st / n;
        const float o_var = fmaxf(sm2 / n - o_mean * o_mean, 0.f);
        const float o_std = sqrtf(fmaxf(o_var, 0.01f));
        const float t0var = fmaxf(st2 / n - t0m * t0m, 0.f);
        const float t_std = sqrtf(fmaxf(gamma * gamma * t0var, 0.01f));
        const float gdyn = fminf(fmaxf(o_std / t_std, 0.8f), 1.2f);
        const float c1 = gdyn * gamma;
        coef[b] = o_mean - c1 * t0m;   // c0
        coef[BATCH + b] = c1;          // c1
    }
}

// ---------------- residual + final clamp + softmax -> bf16 attn ----------
__global__ __launch_bounds__(256) void softmax_kernel(
    const float* __restrict__ scores,      // [B,H,S,S]
    const float* __restrict__ t0,          // [B,S,S]
    const float* __restrict__ coef,        // c0[B], c1[B]
    unsigned short* __restrict__ attn)     // [B,H,S,S] bf16
{
    const int r = blockIdx.x;              // (b*H+h)*S + i
    const int i = r & 511;
    const int bh = r >> 9;
    const int b = bh >> 3;
    const float c0 = coef[b], c1 = coef[BATCH + b];
    const float* row = scores + (long)r * SEQ;
    const float* trow = t0 + ((long)b * SEQ + i) * SEQ;
    const int tid = threadIdx.x;
    __shared__ float sred[4];

    float v[2], lmax = -1e30f;
    #pragma unroll
    for (int u = 0; u < 2; u++) {
        const int j = tid + u * 256;
        float sv = row[j] + ALPHA * (c0 + c1 * trow[j]);
        sv = fminf(fmaxf(sv, -15.f), 15.f);
        v[u] = sv;
        lmax = fmaxf(lmax, sv);
    }
    const float rmax = blockReduceMax(lmax, sred);
    float ex[2], lsum = 0.f;
    #pragma unroll
    for (int u = 0; u < 2; u++) { ex[u] = expf(v[u] - rmax); lsum += ex[u]; }
    const float rsum = blockReduceSum(lsum, sred);
    const float inv = 1.f / rsum;
    #pragma unroll
    for (int u = 0; u < 2; u++)
        attn[(long)r * SEQ + tid + u * 256] = f2bf(ex[u] * inv);
}

// -------------------------------------------------------------------------
extern "C" void kernel_launch(void* const* d_in, const int* in_sizes, int n_in,
                              void* d_out, int out_size, void* d_ws, size_t ws_size,
                              hipStream_t stream) {
    const float* x  = (const float*)d_in[0];
    const float* wq = (const float*)d_in[1];
    const float* bq = (const float*)d_in[2];
    const float* wk = (const float*)d_in[3];
    const float* bk = (const float*)d_in[4];
    const float* wv = (const float*)d_in[5];
    const float* bv = (const float*)d_in[6];
    const float* wo = (const float*)d_in[7];
    const float* bo = (const float*)d_in[8];
    const float* w1 = (const float*)d_in[9];
    const float* b1 = (const float*)d_in[10];
    const float* w2 = (const float*)d_in[11];
    const float* b2 = (const float*)d_in[12];
    float* out = (float*)d_out;

    // ---- workspace layout ----
    char* wsb = (char*)d_ws;
    float*  scores   = (float*)wsb;                    // 32 MB  [B,H,S,S]
    float*  t0       = scores + 8388608;               // 4 MB   [B,S,S]
    float4* partials = (float4*)(t0 + 1048576);        // 32 KB
    float*  coef     = (float*)(partials + 2048);      // 8
    float*  lutbuf   = coef + 8;                       // LUTN+1
    unsigned short* u16 = (unsigned short*)(wsb + (40u << 20));
    unsigned short* xhi   = u16;                       // 1048576
    unsigned short* xlo   = xhi + 1048576;
    unsigned short* wqkvh = xlo + 1048576;             // 786432 (wq|wk|wv)
    unsigned short* wqkvl = wqkvh + 786432;
    unsigned short* woh   = wqkvl + 786432;            // 262144
    unsigned short* qhi   = woh + 262144;              // 1048576 [B,H,S,DH]
    unsigned short* qlo   = qhi + 1048576;
    unsigned short* khi   = qlo + 1048576;
    unsigned short* klo   = khi + 1048576;
    unsigned short* vT    = klo + 1048576;             // [B,H,DH,S]
    unsigned short* attn  = vT + 1048576;              // 8388608 [B,H,S,S]
    unsigned short* otmp  = attn + 8388608;            // 1048576 [B,S,E]

    // fused prep: LUT + all splits/casts (1 launch instead of 6)
    prep_kernel<<<dim3(9 + 8192), dim3(256), 0, stream>>>(
        x, wq, wk, wv, wo, w1, b1, w2, b2,
        xhi, xlo, wqkvh, wqkvl, woh, lutbuf);

    // fused QKV projection (split x * split w, 3-MFMA, pipelined)
    gemm_qkv<<<dim3(24, 32), dim3(256), 0, stream>>>(
        xhi, xlo, wqkvh, wqkvl, bq, bk, bv, qhi, qlo, khi, klo, vT);

    // scores = q @ k^T per (b,h) (split q * split k), clamp
    gemm_scores<<<dim3(8, 8, 32), dim3(256), 0, stream>>>(
        qhi, qlo, khi, klo, scores);

    // autopoietic transform (LUT-based, atomic-free)
    transform_kernel<<<dim3(BATCH * SEQ), dim3(256), 0, stream>>>(
        scores, lutbuf, t0, partials);

    stats_kernel<<<dim3(BATCH), dim3(256), 0, stream>>>(partials, coef);

    // residual + clamp + softmax -> bf16 attn
    softmax_kernel<<<dim3(BATCH * NH * SEQ), dim3(256), 0, stream>>>(
        scores, t0, coef, attn);

    // out_tmp = attn @ v  (single bf16, pipelined)
    gemm_attnv<<<dim3(1, 8, 32), dim3(256), 0, stream>>>(attn, vT, otmp);

    // out = out_tmp @ wo^T + bo  (single bf16, fp32 out, pipelined)
    gemm_proj<<<dim3(8, 32), dim3(256), 0, stream>>>(otmp, woh, bo, out);
}

// Round 6
// 174.864 us; speedup vs baseline: 2.3037x; 1.1453x over previous
//
#include <hip/hip_runtime.h>
#include <math.h>

// Problem constants (reference: B=4, S=512, E=512, H=8, DH=64, HID=128)
#define BATCH 4
#define SEQ   512
#define EMB   512
#define NH    8
#define DHD   64
#define HIDN  128
#define ALPHA 0.1f
#define EPSS  0.05f

// LUT for the pointwise conv-chain -> sigmoid function of `scaled`
#define LUTN  2048
#define XMIN  (-0.4f)
#define XSTEP (0.8f / LUTN)

typedef __attribute__((ext_vector_type(8))) short  bf16x8;
typedef __attribute__((ext_vector_type(4))) float  f32x4;
#define MFMA(a,b,c) __builtin_amdgcn_mfma_f32_16x16x32_bf16((a),(b),(c),0,0,0)

__device__ __forceinline__ unsigned short f2bf(float f) {
    union { float f; unsigned u; } v; v.f = f;
    unsigned r = v.u + 0x7fffu + ((v.u >> 16) & 1u);   // RNE; inputs finite
    return (unsigned short)(r >> 16);
}
__device__ __forceinline__ float bf2f(unsigned short h) {
    union { unsigned u; float f; } v; v.u = ((unsigned)h) << 16;
    return v.f;
}

// async global->LDS, 16B per lane; LDS dst = uniform base + lane*16
__device__ __forceinline__ void async_lds16(const unsigned short* g, unsigned short* l) {
    __builtin_amdgcn_global_load_lds(
        (const __attribute__((address_space(1))) void*)g,
        (__attribute__((address_space(3))) void*)l, 16, 0, 0);
}

// ---------------- m97-style GEMM core ------------------------------------
// NT: C[m,n] = sum_k A[m,k]*B[n,k], A/B row-major bf16, K = KSTEPS*32.
// Block: 256 thr / 4 waves as 2x2; wave tile 32 x (UN*16); block 64 x (UN*32).
// BK=32 staged via global_load_lds with XOR chunk swizzle (2-way conflicts).
template<int KSTEPS, int UN>
__device__ __forceinline__ void gemm_core(
    const unsigned short* __restrict__ A, const unsigned short* __restrict__ B,
    int m0, int n0, unsigned short* sA, unsigned short* sB, f32x4 acc[2][4])
{
    const int K = KSTEPS * 32;
    const int tid = threadIdx.x, w = tid >> 6, lane = tid & 63;
    const int quad = lane >> 4, r = lane & 15;
    const int wm = w >> 1, wn = w & 1;
    const int lrow = lane >> 2, lc = lane & 3;
    const int sc = lc ^ (lrow & 3);              // swizzled global chunk
    const unsigned short* ag  = A + (long)(m0 + w * 16 + lrow) * K + sc * 8;
    const unsigned short* bg0 = B + (long)(n0 + w * 16 + lrow) * K + sc * 8;
    const unsigned short* bg1 = (UN == 4)
        ? B + (long)(n0 + (w + 4) * 16 + lrow) * K + sc * 8 : (const unsigned short*)0;
    unsigned short* dA  = sA + w * 512;
    unsigned short* dB0 = sB + w * 512;
    unsigned short* dB1 = sB + (w + 4) * 512;
    const int cs = quad ^ (r & 3);               // swizzled chunk for ds_read

    for (int s = 0; s < KSTEPS; s++) {
        const int k0 = s * 32;
        async_lds16(ag + k0, dA);
        async_lds16(bg0 + k0, dB0);
        if (UN == 4) async_lds16(bg1 + k0, dB1);
        __syncthreads();                         // drain async, tile visible
        bf16x8 af[2], bf[4];
        #pragma unroll
        for (int t = 0; t < 2; t++)
            af[t] = *(const bf16x8*)(sA + (wm * 32 + t * 16 + r) * 32 + cs * 8);
        #pragma unroll
        for (int u = 0; u < UN; u++)
            bf[u] = *(const bf16x8*)(sB + (wn * UN * 16 + u * 16 + r) * 32 + cs * 8);
        #pragma unroll
        for (int t = 0; t < 2; t++)
            #pragma unroll
            for (int u = 0; u < UN; u++)
                acc[t][u] = MFMA(af[t], bf[u], acc[t][u]);
        __syncthreads();                         // protect LDS before next stage
    }
}

// ---------------- fused QKV projection -----------------------------------
// A = x_ext [2048,1536]=[xh|xl|xh]; B = w_ext [1536,1536]=[wh|wh|wl]
// -> exact 3-term compensated product. Grid (12, 32), block 64x128.
__global__ __launch_bounds__(256) void gemm_qkv(
    const unsigned short* __restrict__ x_ext, const unsigned short* __restrict__ w_ext,
    const float* __restrict__ bq, const float* __restrict__ bk, const float* __restrict__ bv,
    unsigned short* __restrict__ q_ext, unsigned short* __restrict__ k_ext,
    unsigned short* __restrict__ vT)
{
    __shared__ __align__(16) unsigned short sA[64 * 32];
    __shared__ __align__(16) unsigned short sB[128 * 32];
    __shared__ float sC[64 * 132];

    const int m0 = blockIdx.y * 64, n0 = blockIdx.x * 128;
    f32x4 acc[2][4] = {};
    gemm_core<48, 4>(x_ext, w_ext, m0, n0, sA, sB, acc);

    const int tid = threadIdx.x, w = tid >> 6, lane = tid & 63;
    const int quad = lane >> 4, r = lane & 15;
    const int wm = w >> 1, wn = w & 1;
    #pragma unroll
    for (int t = 0; t < 2; t++)
        #pragma unroll
        for (int u = 0; u < 4; u++)
            #pragma unroll
            for (int g = 0; g < 4; g++)
                sC[(wm * 32 + t * 16 + quad * 4 + g) * 132 + wn * 64 + u * 16 + r] = acc[t][u][g];
    __syncthreads();

    const int which = n0 >> 9;       // 0:q 1:k 2:v (uniform; 128 | 512)
    const int n0l = n0 & 511;
    const int h0 = n0l >> 6;
    const int b = m0 >> 9, s0 = m0 & 511;

    if (which < 2) {
        const float scl = (which == 0) ? 0.125f : 1.0f;
        const float* bias = (which == 0) ? bq : bk;
        unsigned* dst = (unsigned*)((which == 0) ? q_ext : k_ext);
        #pragma unroll
        for (int seg = 0; seg < 3; seg++) {
            // q_ext row = [hi | lo | hi]; k_ext row = [hi | hi | lo]
            const bool lo = (which == 0) ? (seg == 1) : (seg == 2);
            for (int it = 0; it < 16; it++) {
                const int idx = it * 256 + tid;        // 0..4095
                const int row = idx >> 5;              // 0..127 = hl*64+sl
                const int hl = row >> 6, sl = row & 63;
                const int jc = idx & 31;
                const int nc = hl * 64 + jc * 2;
                float v0 = (sC[sl * 132 + nc]     + bias[n0l + nc])     * scl;
                float v1 = (sC[sl * 132 + nc + 1] + bias[n0l + nc + 1]) * scl;
                unsigned short a0 = f2bf(v0), a1 = f2bf(v1);
                if (lo) { a0 = f2bf(v0 - bf2f(a0)); a1 = f2bf(v1 - bf2f(a1)); }
                const long orow = (long)(b * NH + h0 + hl) * SEQ + s0 + sl;
                dst[orow * 96 + seg * 32 + jc] = (unsigned)a0 | ((unsigned)a1 << 16);
            }
        }
    } else {
        unsigned* dst = (unsigned*)vT;
        for (int it = 0; it < 16; it++) {
            const int idx = it * 256 + tid;
            const int row = idx >> 5;                  // hl*64 + d
            const int hl = row >> 6, d = row & 63;
            const int jc = idx & 31;
            const int sl = jc * 2;
            const float bvv = bv[n0l + hl * 64 + d];
            const float v0 = sC[sl * 132 + hl * 64 + d] + bvv;
            const float v1 = sC[(sl + 1) * 132 + hl * 64 + d] + bvv;
            const long orow = (long)(b * NH + h0 + hl) * DHD + d;
            dst[orow * 256 + (s0 >> 1) + jc] = (unsigned)f2bf(v0) | ((unsigned)f2bf(v1) << 16);
        }
    }
}

// ---------------- scores = q_ext @ k_ext^T per (b,h), K=192, clamp -------
__global__ __launch_bounds__(256) void gemm_scores(
    const unsigned short* __restrict__ q_ext, const unsigned short* __restrict__ k_ext,
    float* __restrict__ scores)
{
    __shared__ __align__(16) unsigned short sA[64 * 32];
    __shared__ __align__(16) unsigned short sB[128 * 32];
    const int z = blockIdx.z;
    const int m0 = blockIdx.y * 64, n0 = blockIdx.x * 128;
    f32x4 acc[2][4] = {};
    gemm_core<6, 4>(q_ext + (long)z * SEQ * 192, k_ext + (long)z * SEQ * 192,
                    m0, n0, sA, sB, acc);
    float* C = scores + (long)z * SEQ * SEQ;
    const int tid = threadIdx.x, w = tid >> 6, lane = tid & 63;
    const int quad = lane >> 4, r = lane & 15;
    const int wm = w >> 1, wn = w & 1;
    #pragma unroll
    for (int t = 0; t < 2; t++)
        #pragma unroll
        for (int u = 0; u < 4; u++)
            #pragma unroll
            for (int g = 0; g < 4; g++) {
                const int m = m0 + wm * 32 + t * 16 + quad * 4 + g;
                const int n = n0 + wn * 64 + u * 16 + r;
                C[(long)m * SEQ + n] = fminf(fmaxf(acc[t][u][g], -15.f), 15.f);
            }
}

// ---------------- out_tmp = attn @ v, per (b,h) --------------------------
__global__ __launch_bounds__(256) void gemm_attnv(
    const unsigned short* __restrict__ attn, const unsigned short* __restrict__ vT,
    unsigned short* __restrict__ otmp)
{
    __shared__ __align__(16) unsigned short sA[64 * 32];
    __shared__ __align__(16) unsigned short sB[64 * 32];
    __shared__ float sC[64 * 66];
    const int z = blockIdx.z;
    const int m0 = blockIdx.y * 64;
    f32x4 acc[2][4] = {};
    gemm_core<16, 2>(attn + (long)z * SEQ * SEQ, vT + (long)z * DHD * SEQ,
                     m0, 0, sA, sB, acc);
    const int tid = threadIdx.x, w = tid >> 6, lane = tid & 63;
    const int quad = lane >> 4, r = lane & 15;
    const int wm = w >> 1, wn = w & 1;
    #pragma unroll
    for (int t = 0; t < 2; t++)
        #pragma unroll
        for (int u = 0; u < 2; u++)
            #pragma unroll
            for (int g = 0; g < 4; g++)
                sC[(wm * 32 + t * 16 + quad * 4 + g) * 66 + wn * 32 + u * 16 + r] = acc[t][u][g];
    __syncthreads();
    const int b = z >> 3, h = z & 7;
    unsigned* dst = (unsigned*)otmp;
    for (int it = 0; it < 8; it++) {
        const int idx = it * 256 + tid;
        const int sr = idx >> 5, jc = idx & 31;
        const float v0 = sC[sr * 66 + jc * 2], v1 = sC[sr * 66 + jc * 2 + 1];
        dst[((long)(b * SEQ + m0 + sr)) * 256 + h * 32 + jc] =
            (unsigned)f2bf(v0) | ((unsigned)f2bf(v1) << 16);
    }
}

// ---------------- out = out_tmp @ wo^T + bo ------------------------------
__global__ __launch_bounds__(256) void gemm_proj(
    const unsigned short* __restrict__ otmp, const unsigned short* __restrict__ woh,
    const float* __restrict__ bo, float* __restrict__ out)
{
    __shared__ __align__(16) unsigned short sA[64 * 32];
    __shared__ __align__(16) unsigned short sB[64 * 32];
    const int m0 = blockIdx.y * 64, n0 = blockIdx.x * 64;
    f32x4 acc[2][4] = {};
    gemm_core<16, 2>(otmp, woh, m0, n0, sA, sB, acc);
    const int tid = threadIdx.x, w = tid >> 6, lane = tid & 63;
    const int quad = lane >> 4, r = lane & 15;
    const int wm = w >> 1, wn = w & 1;
    #pragma unroll
    for (int t = 0; t < 2; t++)
        #pragma unroll
        for (int u = 0; u < 2; u++)
            #pragma unroll
            for (int g = 0; g < 4; g++) {
                const int m = m0 + wm * 32 + t * 16 + quad * 4 + g;
                const int n = n0 + wn * 32 + u * 16 + r;
                out[(long)m * EMB + n] = acc[t][u][g] + bo[n];
            }
}

// ---------------- block reduction helpers (blockDim=256, 4 waves) --------
__device__ __forceinline__ float blockReduceMax(float v, float* sred) {
    #pragma unroll
    for (int o = 32; o > 0; o >>= 1) v = fmaxf(v, __shfl_down(v, o));
    __syncthreads();
    if ((threadIdx.x & 63) == 0) sred[threadIdx.x >> 6] = v;
    __syncthreads();
    return fmaxf(fmaxf(sred[0], sred[1]), fmaxf(sred[2], sred[3]));
}
__device__ __forceinline__ float blockReduceSum(float v, float* sred) {
    #pragma unroll
    for (int o = 32; o > 0; o >>= 1) v += __shfl_down(v, o);
    __syncthreads();
    if ((threadIdx.x & 63) == 0) sred[threadIdx.x >> 6] = v;
    __syncthreads();
    return (sred[0] + sred[1]) + (sred[2] + sred[3]);
}

// ---------------- fused prep: LUT + ext-K split builds -------------------
__global__ __launch_bounds__(256) void prep_kernel(
    const float* __restrict__ x,
    const float* __restrict__ wq, const float* __restrict__ wk,
    const float* __restrict__ wv, const float* __restrict__ wo,
    const float* __restrict__ w1, const float* __restrict__ b1,
    const float* __restrict__ w2, const float* __restrict__ b2,
    unsigned short* __restrict__ x_ext, unsigned short* __restrict__ w_ext,
    unsigned short* __restrict__ woh, float* __restrict__ lut)
{
    const int blk = blockIdx.x;
    if (blk < 9) {
        const int i = blk * 256 + threadIdx.x;
        if (i > LUTN) return;
        const float xv = XMIN + i * XSTEP;
        float a = 0.f;
        for (int h = 0; h < HIDN; h++) {
            float hv = xv * w1[h] + b1[h];
            hv = fminf(fmaxf(hv, -5.f), 5.f);
            hv = fmaxf(hv, 0.f);
            a += hv * w2[h];
        }
        a += b2[0];
        a = fminf(fmaxf(a, -5.f), 5.f);
        const float taylor = fminf(fmaxf(1.f + 2.5f * a, 0.5f), 1.5f);
        lut[i] = 1.f / (1.f + expf(-taylor));
        return;
    }
    const int i = (blk - 9) * 256 + threadIdx.x;  // 0 .. 2097151
    if (i < 1048576) {
        const int m = i >> 9, k = i & 511;
        const float v = x[i];
        const unsigned short h = f2bf(v), l = f2bf(v - bf2f(h));
        const long bb = (long)m * 1536 + k;
        x_ext[bb] = h; x_ext[bb + 512] = l; x_ext[bb + 1024] = h;   // [xh|xl|xh]
    } else if (i < 1835008) {
        const int j = i - 1048576;
        const int n = j >> 9, k = j & 511;
        const float v = (j < 262144) ? wq[j] : (j < 524288 ? wk[j - 262144] : wv[j - 524288]);
        const unsigned short h = f2bf(v), l = f2bf(v - bf2f(h));
        const long bb = (long)n * 1536 + k;
        w_ext[bb] = h; w_ext[bb + 512] = h; w_ext[bb + 1024] = l;   // [wh|wh|wl]
    } else {
        const int j = i - 1835008;
        woh[j] = f2bf(wo[j]);
    }
}

// ---------------- transform kernel: one block per (b,i) row --------------
__global__ __launch_bounds__(256) void transform_kernel(
    const float* __restrict__ scores,      // [B,H,S,S] (clamped)
    const float* __restrict__ lut,         // [LUTN+1]
    float* __restrict__ t0,                // [B,S,S]
    float4* __restrict__ partials)         // [B*S] float4 slots
{
    const int r = blockIdx.x;
    const int b = r >> 9, i = r & 511;
    const int tid = threadIdx.x;

    __shared__ float slut[LUTN + 1];
    __shared__ float sred[4];

    for (int u = tid; u <= LUTN; u += 256) slut[u] = lut[u];

    const float* base = scores + (((long)(b * NH)) * SEQ + i) * SEQ;

    float mv[2], sigv[2], mclip[2];
    float lmax = -1e30f;
    __syncthreads();
    #pragma unroll
    for (int u = 0; u < 2; u++) {
        const int j = tid + u * 256;
        float s = 0.f;
        #pragma unroll
        for (int h = 0; h < NH; h++) s += base[(long)h * SEQ * SEQ + j];
        const float m = s * (1.0f / NH);
        mv[u] = m;
        const float x = fminf(fmaxf(m, -8.f), 8.f) * EPSS;
        float t = (x - XMIN) * (1.0f / XSTEP);
        int idx = (int)t;
        idx = idx < 0 ? 0 : (idx > LUTN - 1 ? LUTN - 1 : idx);
        const float frac = t - (float)idx;
        const float l0 = slut[idx], l1 = slut[idx + 1];
        sigv[u] = l0 + frac * (l1 - l0);
        const float mc = fminf(fmaxf(m, -10.f), 10.f);
        mclip[u] = mc;
        lmax = fmaxf(lmax, mc);
    }

    const float rmax = blockReduceMax(lmax, sred);
    float ex[2], lsum = 0.f;
    #pragma unroll
    for (int u = 0; u < 2; u++) { ex[u] = expf(mclip[u] - rmax); lsum += ex[u]; }
    const float rsum = blockReduceSum(lsum, sred);
    const float inv = 1.f / rsum;

    float hent[2], lmax2 = -1e30f;
    #pragma unroll
    for (int u = 0; u < 2; u++) {
        const float p = ex[u] * inv;
        const float he = -p * logf(p + 1e-6f);
        hent[u] = 3.f * he;
        lmax2 = fmaxf(lmax2, hent[u]);
    }
    const float rmax2 = blockReduceMax(lmax2, sred);
    float ex2[2], lsum2 = 0.f;
    #pragma unroll
    for (int u = 0; u < 2; u++) { ex2[u] = expf(hent[u] - rmax2); lsum2 += ex2[u]; }
    const float rsum2 = blockReduceSum(lsum2, sred);
    const float inv2 = 1.f / rsum2;

    float s_m = 0.f, s_m2 = 0.f, s_t = 0.f, s_t2 = 0.f;
    #pragma unroll
    for (int u = 0; u < 2; u++) {
        const int j = tid + u * 256;
        const float Fm = ex2[u] * inv2;
        const float tv = sigv[u] * Fm;
        t0[((long)b * SEQ + i) * SEQ + j] = tv;
        s_m += mv[u]; s_m2 += mv[u] * mv[u];
        s_t += tv;    s_t2 += tv * tv;
    }
    s_m  = blockReduceSum(s_m,  sred);
    s_m2 = blockReduceSum(s_m2, sred);
    s_t  = blockReduceSum(s_t,  sred);
    s_t2 = blockReduceSum(s_t2, sred);
    if (tid == 0) {
        partials[r] = make_float4(s_m, s_m2, s_t, s_t2);
    }
}

// ---------------- per-batch stats reduction -> c0,c1 ---------------------
__global__ __launch_bounds__(256) void stats_kernel(
    const float4* __restrict__ partials, float* __restrict__ coef)
{
    const int b = blockIdx.x;
    const int tid = threadIdx.x;
    __shared__ float sred[4];

    const float4 p0 = partials[b * SEQ + tid];
    const float4 p1 = partials[b * SEQ + tid + 256];
    float sm  = p0.x + p1.x;
    float sm2 = p0.y + p1.y;
    float st  = p0.z + p1.z;
    float st2 = p0.w + p1.w;
    sm  = blockReduceSum(sm,  sred);
    sm2 = blockReduceSum(sm2, sred);
    st  = blockReduceSum(st,  sred);
    st2 = blockReduceSum(st2, sred);

    if (tid == 0) {
        const float n = (float)SEQ * (float)SEQ;
        const float e_o = sqrtf(sm2) + 1e-4f;
        const float e_t = sqrtf(st2) + 1e-4f;
        const float gamma = fminf(fmaxf(e_o / e_t, 0.8f), 1.2f);
        const float o_mean = sm / n, t0m = st / n;
        const float o_var = fmaxf(sm2 / n - o_mean * o_mean, 0.f);
        const float o_std = sqrtf(fmaxf(o_var, 0.01f));
        const float t0var = fmaxf(st2 / n - t0m * t0m, 0.f);
        const float t_std = sqrtf(fmaxf(gamma * gamma * t0var, 0.01f));
        const float gdyn = fminf(fmaxf(o_std / t_std, 0.8f), 1.2f);
        const float c1 = gdyn * gamma;
        coef[b] = o_mean - c1 * t0m;   // c0
        coef[BATCH + b] = c1;          // c1
    }
}

// ---------------- residual + final clamp + softmax -> bf16 attn ----------
__global__ __launch_bounds__(256) void softmax_kernel(
    const float* __restrict__ scores,      // [B,H,S,S]
    const float* __restrict__ t0,          // [B,S,S]
    const float* __restrict__ coef,        // c0[B], c1[B]
    unsigned short* __restrict__ attn)     // [B,H,S,S] bf16
{
    const int r = blockIdx.x;              // (b*H+h)*S + i
    const int i = r & 511;
    const int bh = r >> 9;
    const int b = bh >> 3;
    const float c0 = coef[b], c1 = coef[BATCH + b];
    const float* row = scores + (long)r * SEQ;
    const float* trow = t0 + ((long)b * SEQ + i) * SEQ;
    const int tid = threadIdx.x;
    __shared__ float sred[4];

    float v[2], lmax = -1e30f;
    #pragma unroll
    for (int u = 0; u < 2; u++) {
        const int j = tid + u * 256;
        float sv = row[j] + ALPHA * (c0 + c1 * trow[j]);
        sv = fminf(fmaxf(sv, -15.f), 15.f);
        v[u] = sv;
        lmax = fmaxf(lmax, sv);
    }
    const float rmax = blockReduceMax(lmax, sred);
    float ex[2], lsum = 0.f;
    #pragma unroll
    for (int u = 0; u < 2; u++) { ex[u] = expf(v[u] - rmax); lsum += ex[u]; }
    const float rsum = blockReduceSum(lsum, sred);
    const float inv = 1.f / rsum;
    #pragma unroll
    for (int u = 0; u < 2; u++)
        attn[(long)r * SEQ + tid + u * 256] = f2bf(ex[u] * inv);
}

// -------------------------------------------------------------------------
extern "C" void kernel_launch(void* const* d_in, const int* in_sizes, int n_in,
                              void* d_out, int out_size, void* d_ws, size_t ws_size,
                              hipStream_t stream) {
    const float* x  = (const float*)d_in[0];
    const float* wq = (const float*)d_in[1];
    const float* bq = (const float*)d_in[2];
    const float* wk = (const float*)d_in[3];
    const float* bk = (const float*)d_in[4];
    const float* wv = (const float*)d_in[5];
    const float* bv = (const float*)d_in[6];
    const float* wo = (const float*)d_in[7];
    const float* bo = (const float*)d_in[8];
    const float* w1 = (const float*)d_in[9];
    const float* b1 = (const float*)d_in[10];
    const float* w2 = (const float*)d_in[11];
    const float* b2 = (const float*)d_in[12];
    float* out = (float*)d_out;

    // ---- workspace layout (total ~68.3 MB) ----
    char* wsb = (char*)d_ws;
    float*  scores   = (float*)wsb;                    // 32 MB
    float*  t0       = scores + 8388608;               // 4 MB
    float4* partials = (float4*)(t0 + 1048576);        // 32 KB
    float*  coef     = (float*)(partials + 2048);
    float*  lutbuf   = coef + 8;
    unsigned short* u16 = (unsigned short*)(wsb + (40u << 20));
    unsigned short* x_ext = u16;                       // 3,145,728  [2048,1536]
    unsigned short* w_ext = x_ext + 3145728;           // 2,359,296  [1536,1536]
    unsigned short* q_ext = w_ext + 2359296;           // 3,145,728  [B*H*S,192]
    unsigned short* attn  = u16;                       // overlay (x/w/q dead by softmax)
    unsigned short* k_ext = q_ext + 3145728;           // 3,145,728
    unsigned short* vT    = k_ext + 3145728;           // 1,048,576  [B,H,DH,S]
    unsigned short* otmp  = vT + 1048576;              // 1,048,576  [B*S, E]
    unsigned short* woh   = otmp + 1048576;            //   262,144  [E,E]

    // prep: LUT + ext-K split builds (1 launch)
    prep_kernel<<<dim3(9 + 8192), dim3(256), 0, stream>>>(
        x, wq, wk, wv, wo, w1, b1, w2, b2, x_ext, w_ext, woh, lutbuf);

    // fused QKV projection (compensated bf16, K=1536)
    gemm_qkv<<<dim3(12, 32), dim3(256), 0, stream>>>(
        x_ext, w_ext, bq, bk, bv, q_ext, k_ext, vT);

    // scores = q @ k^T per (b,h) (compensated, K=192), clamp
    gemm_scores<<<dim3(4, 8, 32), dim3(256), 0, stream>>>(q_ext, k_ext, scores);

    // autopoietic transform (LUT-based, atomic-free)
    transform_kernel<<<dim3(BATCH * SEQ), dim3(256), 0, stream>>>(
        scores, lutbuf, t0, partials);

    stats_kernel<<<dim3(BATCH), dim3(256), 0, stream>>>(partials, coef);

    // residual + clamp + softmax -> bf16 attn (overlays dead buffers)
    softmax_kernel<<<dim3(BATCH * NH * SEQ), dim3(256), 0, stream>>>(
        scores, t0, coef, attn);

    // out_tmp = attn @ v  (single bf16, K=512)
    gemm_attnv<<<dim3(1, 8, 32), dim3(256), 0, stream>>>(attn, vT, otmp);

    // out = out_tmp @ wo^T + bo  (single bf16, fp32 out, K=512)
    gemm_proj<<<dim3(8, 32), dim3(256), 0, stream>>>(otmp, woh, bo, out);
}

// Round 7
// 164.371 us; speedup vs baseline: 2.4507x; 1.0638x over previous
//
#include <hip/hip_runtime.h>
#include <math.h>

// Problem constants (reference: B=4, S=512, E=512, H=8, DH=64, HID=128)
#define BATCH 4
#define SEQ   512
#define EMB   512
#define NH    8
#define DHD   64
#define HIDN  128
#define ALPHA 0.1f
#define EPSS  0.05f

// LUT for the pointwise conv-chain -> sigmoid function of `scaled`
#define LUTN  2048
#define XMIN  (-0.4f)
#define XSTEP (0.8f / LUTN)

typedef __attribute__((ext_vector_type(8))) short  bf16x8;
typedef __attribute__((ext_vector_type(4))) float  f32x4;
#define MFMA(a,b,c) __builtin_amdgcn_mfma_f32_16x16x32_bf16((a),(b),(c),0,0,0)

__device__ __forceinline__ unsigned short f2bf(float f) {
    union { float f; unsigned u; } v; v.f = f;
    unsigned r = v.u + 0x7fffu + ((v.u >> 16) & 1u);   // RNE; inputs finite
    return (unsigned short)(r >> 16);
}
__device__ __forceinline__ float bf2f(unsigned short h) {
    union { unsigned u; float f; } v; v.u = ((unsigned)h) << 16;
    return v.f;
}

// async global->LDS, 16B per lane; LDS dst = uniform base + lane*16
__device__ __forceinline__ void async_lds16(const unsigned short* g, unsigned short* l) {
    __builtin_amdgcn_global_load_lds(
        (const __attribute__((address_space(1))) void*)g,
        (__attribute__((address_space(3))) void*)l, 16, 0, 0);
}

// ---------------- m97-style GEMM core ------------------------------------
// NT: C[m,n] = sum_k A[m,k]*B[n,k], A/B row-major bf16, K = KSTEPS*32.
// Block: 256 thr / 4 waves as 2x2; wave tile 32 x (UN*16); block 64 x (UN*32).
// BK=32 staged via global_load_lds with XOR chunk swizzle.
template<int KSTEPS, int UN>
__device__ __forceinline__ void gemm_core(
    const unsigned short* __restrict__ A, const unsigned short* __restrict__ B,
    int m0, int n0, unsigned short* sA, unsigned short* sB, f32x4 acc[2][4])
{
    const int K = KSTEPS * 32;
    const int tid = threadIdx.x, w = tid >> 6, lane = tid & 63;
    const int quad = lane >> 4, r = lane & 15;
    const int wm = w >> 1, wn = w & 1;
    const int lrow = lane >> 2, lc = lane & 3;
    const int sc = lc ^ (lrow & 3);              // swizzled global chunk
    const unsigned short* ag  = A + (long)(m0 + w * 16 + lrow) * K + sc * 8;
    const unsigned short* bg0 = B + (long)(n0 + w * 16 + lrow) * K + sc * 8;
    const unsigned short* bg1 = (UN == 4)
        ? B + (long)(n0 + (w + 4) * 16 + lrow) * K + sc * 8 : (const unsigned short*)0;
    unsigned short* dA  = sA + w * 512;
    unsigned short* dB0 = sB + w * 512;
    unsigned short* dB1 = sB + (w + 4) * 512;
    const int cs = quad ^ (r & 3);               // swizzled chunk for ds_read

    for (int s = 0; s < KSTEPS; s++) {
        const int k0 = s * 32;
        async_lds16(ag + k0, dA);
        async_lds16(bg0 + k0, dB0);
        if (UN == 4) async_lds16(bg1 + k0, dB1);
        __syncthreads();                         // drain async, tile visible
        bf16x8 af[2], bf[4];
        #pragma unroll
        for (int t = 0; t < 2; t++)
            af[t] = *(const bf16x8*)(sA + (wm * 32 + t * 16 + r) * 32 + cs * 8);
        #pragma unroll
        for (int u = 0; u < UN; u++)
            bf[u] = *(const bf16x8*)(sB + (wn * UN * 16 + u * 16 + r) * 32 + cs * 8);
        #pragma unroll
        for (int t = 0; t < 2; t++)
            #pragma unroll
            for (int u = 0; u < UN; u++)
                acc[t][u] = MFMA(af[t], bf[u], acc[t][u]);
        __syncthreads();                         // protect LDS before next stage
    }
}

// ---------------- fused QKV projection -----------------------------------
// A = x_ext [2048,1536]=[xh|xl|xh]; B = w_ext [1536,1536]=[wh|wh|wl]
// -> exact 3-term compensated product. 64x64 tiles, grid (24,32) = 768
// blocks = 3 blocks/CU (25 KB LDS) so barrier drains are covered by
// co-resident blocks (m114 overlap).
__global__ __launch_bounds__(256) void gemm_qkv(
    const unsigned short* __restrict__ x_ext, const unsigned short* __restrict__ w_ext,
    const float* __restrict__ bq, const float* __restrict__ bk, const float* __restrict__ bv,
    unsigned short* __restrict__ q_ext, unsigned short* __restrict__ k_ext,
    unsigned short* __restrict__ vT)
{
    __shared__ __align__(16) unsigned short sA[64 * 32];
    __shared__ __align__(16) unsigned short sB[64 * 32];
    __shared__ float sC[64 * 68];

    const int m0 = blockIdx.y * 64, n0 = blockIdx.x * 64;
    f32x4 acc[2][4] = {};
    gemm_core<48, 2>(x_ext, w_ext, m0, n0, sA, sB, acc);

    const int tid = threadIdx.x, w = tid >> 6, lane = tid & 63;
    const int quad = lane >> 4, r = lane & 15;
    const int wm = w >> 1, wn = w & 1;
    #pragma unroll
    for (int t = 0; t < 2; t++)
        #pragma unroll
        for (int u = 0; u < 2; u++)
            #pragma unroll
            for (int g = 0; g < 4; g++)
                sC[(wm * 32 + t * 16 + quad * 4 + g) * 68 + wn * 32 + u * 16 + r] = acc[t][u][g];
    __syncthreads();

    const int which = n0 >> 9;       // 0:q 1:k 2:v
    const int n0l = n0 & 511;        // = h0*64
    const int h0 = n0l >> 6;
    const int b = m0 >> 9, s0 = m0 & 511;

    if (which < 2) {
        const float scl = (which == 0) ? 0.125f : 1.0f;
        const float* bias = (which == 0) ? bq : bk;
        unsigned* dst = (unsigned*)((which == 0) ? q_ext : k_ext);
        #pragma unroll
        for (int seg = 0; seg < 3; seg++) {
            // q_ext row = [hi | lo | hi]; k_ext row = [hi | hi | lo]
            const bool lo = (which == 0) ? (seg == 1) : (seg == 2);
            #pragma unroll
            for (int it = 0; it < 8; it++) {
                const int idx = it * 256 + tid;        // 0..2047
                const int sl = idx >> 5;               // s-row 0..63
                const int jc = idx & 31;               // d pair
                const int nc = jc * 2;
                float v0 = (sC[sl * 68 + nc]     + bias[n0l + nc])     * scl;
                float v1 = (sC[sl * 68 + nc + 1] + bias[n0l + nc + 1]) * scl;
                unsigned short a0 = f2bf(v0), a1 = f2bf(v1);
                if (lo) { a0 = f2bf(v0 - bf2f(a0)); a1 = f2bf(v1 - bf2f(a1)); }
                const long orow = (long)(b * NH + h0) * SEQ + s0 + sl;
                dst[orow * 96 + seg * 32 + jc] = (unsigned)a0 | ((unsigned)a1 << 16);
            }
        }
    } else {
        unsigned* dst = (unsigned*)vT;
        #pragma unroll
        for (int it = 0; it < 8; it++) {
            const int idx = it * 256 + tid;
            const int d = idx >> 5;                    // 0..63
            const int jc = idx & 31;                   // s pair
            const int sl = jc * 2;
            const float bvv = bv[n0l + d];
            const float v0 = sC[sl * 68 + d] + bvv;
            const float v1 = sC[(sl + 1) * 68 + d] + bvv;
            const long orow = (long)(b * NH + h0) * DHD + d;
            dst[orow * 256 + (s0 >> 1) + jc] = (unsigned)f2bf(v0) | ((unsigned)f2bf(v1) << 16);
        }
    }
}

// ---------------- scores = q_ext @ k_ext^T per (b,h), K=192, clamp -------
__global__ __launch_bounds__(256) void gemm_scores(
    const unsigned short* __restrict__ q_ext, const unsigned short* __restrict__ k_ext,
    float* __restrict__ scores)
{
    __shared__ __align__(16) unsigned short sA[64 * 32];
    __shared__ __align__(16) unsigned short sB[128 * 32];
    const int z = blockIdx.z;
    const int m0 = blockIdx.y * 64, n0 = blockIdx.x * 128;
    f32x4 acc[2][4] = {};
    gemm_core<6, 4>(q_ext + (long)z * SEQ * 192, k_ext + (long)z * SEQ * 192,
                    m0, n0, sA, sB, acc);
    float* C = scores + (long)z * SEQ * SEQ;
    const int tid = threadIdx.x, w = tid >> 6, lane = tid & 63;
    const int quad = lane >> 4, r = lane & 15;
    const int wm = w >> 1, wn = w & 1;
    #pragma unroll
    for (int t = 0; t < 2; t++)
        #pragma unroll
        for (int u = 0; u < 4; u++)
            #pragma unroll
            for (int g = 0; g < 4; g++) {
                const int m = m0 + wm * 32 + t * 16 + quad * 4 + g;
                const int n = n0 + wn * 64 + u * 16 + r;
                C[(long)m * SEQ + n] = fminf(fmaxf(acc[t][u][g], -15.f), 15.f);
            }
}

// ---------------- out = out_tmp @ wo^T + bo ------------------------------
__global__ __launch_bounds__(256) void gemm_proj(
    const unsigned short* __restrict__ otmp, const unsigned short* __restrict__ woh,
    const float* __restrict__ bo, float* __restrict__ out)
{
    __shared__ __align__(16) unsigned short sA[64 * 32];
    __shared__ __align__(16) unsigned short sB[64 * 32];
    const int m0 = blockIdx.y * 64, n0 = blockIdx.x * 64;
    f32x4 acc[2][4] = {};
    gemm_core<16, 2>(otmp, woh, m0, n0, sA, sB, acc);
    const int tid = threadIdx.x, w = tid >> 6, lane = tid & 63;
    const int quad = lane >> 4, r = lane & 15;
    const int wm = w >> 1, wn = w & 1;
    #pragma unroll
    for (int t = 0; t < 2; t++)
        #pragma unroll
        for (int u = 0; u < 2; u++)
            #pragma unroll
            for (int g = 0; g < 4; g++) {
                const int m = m0 + wm * 32 + t * 16 + quad * 4 + g;
                const int n = n0 + wn * 32 + u * 16 + r;
                out[(long)m * EMB + n] = acc[t][u][g] + bo[n];
            }
}

// ---------------- block reduction helper (blockDim=256, 4 waves) ---------
__device__ __forceinline__ float blockReduceSum(float v, float* sred) {
    #pragma unroll
    for (int o = 32; o > 0; o >>= 1) v += __shfl_down(v, o);
    __syncthreads();
    if ((threadIdx.x & 63) == 0) sred[threadIdx.x >> 6] = v;
    __syncthreads();
    return (sred[0] + sred[1]) + (sred[2] + sred[3]);
}
__device__ __forceinline__ float blockReduceMax(float v, float* sred) {
    #pragma unroll
    for (int o = 32; o > 0; o >>= 1) v = fmaxf(v, __shfl_down(v, o));
    __syncthreads();
    if ((threadIdx.x & 63) == 0) sred[threadIdx.x >> 6] = v;
    __syncthreads();
    return fmaxf(fmaxf(sred[0], sred[1]), fmaxf(sred[2], sred[3]));
}

// ---------------- fused prep: LUT + ext-K split builds -------------------
__global__ __launch_bounds__(256) void prep_kernel(
    const float* __restrict__ x,
    const float* __restrict__ wq, const float* __restrict__ wk,
    const float* __restrict__ wv, const float* __restrict__ wo,
    const float* __restrict__ w1, const float* __restrict__ b1,
    const float* __restrict__ w2, const float* __restrict__ b2,
    unsigned short* __restrict__ x_ext, unsigned short* __restrict__ w_ext,
    unsigned short* __restrict__ woh, float* __restrict__ lut)
{
    const int blk = blockIdx.x;
    if (blk < 9) {
        const int i = blk * 256 + threadIdx.x;
        if (i > LUTN) return;
        const float xv = XMIN + i * XSTEP;
        float a = 0.f;
        for (int h = 0; h < HIDN; h++) {
            float hv = xv * w1[h] + b1[h];
            hv = fminf(fmaxf(hv, -5.f), 5.f);
            hv = fmaxf(hv, 0.f);
            a += hv * w2[h];
        }
        a += b2[0];
        a = fminf(fmaxf(a, -5.f), 5.f);
        const float taylor = fminf(fmaxf(1.f + 2.5f * a, 0.5f), 1.5f);
        lut[i] = 1.f / (1.f + expf(-taylor));
        return;
    }
    const int i = (blk - 9) * 256 + threadIdx.x;  // 0 .. 2097151
    if (i < 1048576) {
        const int m = i >> 9, k = i & 511;
        const float v = x[i];
        const unsigned short h = f2bf(v), l = f2bf(v - bf2f(h));
        const long bb = (long)m * 1536 + k;
        x_ext[bb] = h; x_ext[bb + 512] = l; x_ext[bb + 1024] = h;   // [xh|xl|xh]
    } else if (i < 1835008) {
        const int j = i - 1048576;
        const int n = j >> 9, k = j & 511;
        const float v = (j < 262144) ? wq[j] : (j < 524288 ? wk[j - 262144] : wv[j - 524288]);
        const unsigned short h = f2bf(v), l = f2bf(v - bf2f(h));
        const long bb = (long)n * 1536 + k;
        w_ext[bb] = h; w_ext[bb + 512] = h; w_ext[bb + 1024] = l;   // [wh|wh|wl]
    } else {
        const int j = i - 1835008;
        woh[j] = f2bf(wo[j]);
    }
}

// ---------------- transform kernel: one block per (b,i) row --------------
__global__ __launch_bounds__(256) void transform_kernel(
    const float* __restrict__ scores,      // [B,H,S,S] (clamped)
    const float* __restrict__ lut,         // [LUTN+1]
    float* __restrict__ t0,                // [B,S,S]
    float4* __restrict__ partials)         // [B*S] float4 slots
{
    const int r = blockIdx.x;
    const int b = r >> 9, i = r & 511;
    const int tid = threadIdx.x;

    __shared__ float slut[LUTN + 1];
    __shared__ float sred[4];

    for (int u = tid; u <= LUTN; u += 256) slut[u] = lut[u];

    const float* base = scores + (((long)(b * NH)) * SEQ + i) * SEQ;

    float mv[2], sigv[2], mclip[2];
    float lmax = -1e30f;
    __syncthreads();
    #pragma unroll
    for (int u = 0; u < 2; u++) {
        const int j = tid + u * 256;
        float s = 0.f;
        #pragma unroll
        for (int h = 0; h < NH; h++) s += base[(long)h * SEQ * SEQ + j];
        const float m = s * (1.0f / NH);
        mv[u] = m;
        const float x = fminf(fmaxf(m, -8.f), 8.f) * EPSS;
        float t = (x - XMIN) * (1.0f / XSTEP);
        int idx = (int)t;
        idx = idx < 0 ? 0 : (idx > LUTN - 1 ? LUTN - 1 : idx);
        const float frac = t - (float)idx;
        const float l0 = slut[idx], l1 = slut[idx + 1];
        sigv[u] = l0 + frac * (l1 - l0);
        const float mc = fminf(fmaxf(m, -10.f), 10.f);
        mclip[u] = mc;
        lmax = fmaxf(lmax, mc);
    }

    const float rmax = blockReduceMax(lmax, sred);
    float ex[2], lsum = 0.f;
    #pragma unroll
    for (int u = 0; u < 2; u++) { ex[u] = expf(mclip[u] - rmax); lsum += ex[u]; }
    const float rsum = blockReduceSum(lsum, sred);
    const float inv = 1.f / rsum;

    float hent[2], lmax2 = -1e30f;
    #pragma unroll
    for (int u = 0; u < 2; u++) {
        const float p = ex[u] * inv;
        const float he = -p * logf(p + 1e-6f);
        hent[u] = 3.f * he;
        lmax2 = fmaxf(lmax2, hent[u]);
    }
    const float rmax2 = blockReduceMax(lmax2, sred);
    float ex2[2], lsum2 = 0.f;
    #pragma unroll
    for (int u = 0; u < 2; u++) { ex2[u] = expf(hent[u] - rmax2); lsum2 += ex2[u]; }
    const float rsum2 = blockReduceSum(lsum2, sred);
    const float inv2 = 1.f / rsum2;

    float s_m = 0.f, s_m2 = 0.f, s_t = 0.f, s_t2 = 0.f;
    #pragma unroll
    for (int u = 0; u < 2; u++) {
        const int j = tid + u * 256;
        const float Fm = ex2[u] * inv2;
        const float tv = sigv[u] * Fm;
        t0[((long)b * SEQ + i) * SEQ + j] = tv;
        s_m += mv[u]; s_m2 += mv[u] * mv[u];
        s_t += tv;    s_t2 += tv * tv;
    }
    s_m  = blockReduceSum(s_m,  sred);
    s_m2 = blockReduceSum(s_m2, sred);
    s_t  = blockReduceSum(s_t,  sred);
    s_t2 = blockReduceSum(s_t2, sred);
    if (tid == 0) {
        partials[r] = make_float4(s_m, s_m2, s_t, s_t2);
    }
}

// ---------------- fused coef + softmax + attn@v --------------------------
// Grid (16 m-tiles of 32 rows, 32 z=(b,h)). Each block: (A) redundantly
// reduce partials -> c0,c1; (B) residual+clamp+softmax its 32 rows into a
// padded LDS bf16 tile (no 32MB attn round-trip); (C) MFMA attn@v with A
// frags from LDS, vT staged via global_load_lds; (D) packed bf16 epilogue.
__global__ __launch_bounds__(256) void softmax_attnv(
    const float* __restrict__ scores,      // [B,H,S,S]
    const float* __restrict__ t0,          // [B,S,S]
    const float4* __restrict__ partials,   // [B*S]
    const unsigned short* __restrict__ vT, // [B,H,DH,S]
    unsigned short* __restrict__ otmp)     // [B*S, E]
{
    __shared__ __align__(16) unsigned short attnS[32 * 520];  // +8 pad
    __shared__ __align__(16) unsigned short sB[64 * 32];
    __shared__ float sC[32 * 66];
    __shared__ float sred[4];

    const int m0 = blockIdx.x * 32;
    const int z  = blockIdx.y;
    const int b  = z >> 3, h = z & 7;
    const int tid = threadIdx.x, wv = tid >> 6, lane = tid & 63;

    // --- phase A: coef (redundant per block, ~32KB L2 read) ---
    const float4 p0 = partials[b * SEQ + tid];
    const float4 p1 = partials[b * SEQ + tid + 256];
    float sm  = blockReduceSum(p0.x + p1.x, sred);
    float sm2 = blockReduceSum(p0.y + p1.y, sred);
    float st  = blockReduceSum(p0.z + p1.z, sred);
    float st2 = blockReduceSum(p0.w + p1.w, sred);
    const float n = (float)SEQ * (float)SEQ;
    const float gamma = fminf(fmaxf((sqrtf(sm2) + 1e-4f) / (sqrtf(st2) + 1e-4f), 0.8f), 1.2f);
    const float o_mean = sm / n, t0m = st / n;
    const float o_std = sqrtf(fmaxf(fmaxf(sm2 / n - o_mean * o_mean, 0.f), 0.01f));
    const float t_std = sqrtf(fmaxf(gamma * gamma * fmaxf(st2 / n - t0m * t0m, 0.f), 0.01f));
    const float gdyn = fminf(fmaxf(o_std / t_std, 0.8f), 1.2f);
    const float c1 = gdyn * gamma;
    const float c0 = o_mean - c1 * t0m;

    // --- phase B: softmax 32 rows -> LDS bf16 tile ---
    const int j0 = lane * 8;
    for (int it = 0; it < 8; it++) {
        const int rowl = it * 4 + wv;
        const float* srow = scores + ((long)z * SEQ + m0 + rowl) * SEQ + j0;
        const float* trow = t0 + ((long)b * SEQ + m0 + rowl) * SEQ + j0;
        const float4 s0 = ((const float4*)srow)[0], s1 = ((const float4*)srow)[1];
        const float4 tt0 = ((const float4*)trow)[0], tt1 = ((const float4*)trow)[1];
        float sv[8] = { s0.x, s0.y, s0.z, s0.w, s1.x, s1.y, s1.z, s1.w };
        const float tvv[8] = { tt0.x, tt0.y, tt0.z, tt0.w, tt1.x, tt1.y, tt1.z, tt1.w };
        float lmax = -1e30f;
        #pragma unroll
        for (int u = 0; u < 8; u++) {
            float s = sv[u] + ALPHA * (c0 + c1 * tvv[u]);
            s = fminf(fmaxf(s, -15.f), 15.f);
            sv[u] = s;
            lmax = fmaxf(lmax, s);
        }
        #pragma unroll
        for (int o = 32; o > 0; o >>= 1) lmax = fmaxf(lmax, __shfl_down(lmax, o));
        lmax = __shfl(lmax, 0);
        float lsum = 0.f;
        #pragma unroll
        for (int u = 0; u < 8; u++) { sv[u] = expf(sv[u] - lmax); lsum += sv[u]; }
        #pragma unroll
        for (int o = 32; o > 0; o >>= 1) lsum += __shfl_down(lsum, o);
        lsum = __shfl(lsum, 0);
        const float inv = 1.f / lsum;
        bf16x8 pk;
        #pragma unroll
        for (int u = 0; u < 8; u++) pk[u] = (short)f2bf(sv[u] * inv);
        *(bf16x8*)(attnS + rowl * 520 + j0) = pk;
    }
    __syncthreads();

    // --- phase C: attn(LDS) @ vT(staged) ---
    const int quad = lane >> 4, r = lane & 15;
    const int wm = wv >> 1, wn = wv & 1;
    const int lrow = lane >> 2, lc = lane & 3;
    const int sc = lc ^ (lrow & 3);
    const int cs = quad ^ (r & 3);
    const unsigned short* bg = vT + (long)z * DHD * SEQ + (long)(wv * 16 + lrow) * SEQ + sc * 8;
    unsigned short* dB = sB + wv * 512;
    f32x4 acc[2] = {};
    for (int kc = 0; kc < 16; kc++) {
        async_lds16(bg + kc * 32, dB);
        __syncthreads();
        const bf16x8 a = *(const bf16x8*)(attnS + (wm * 16 + r) * 520 + kc * 32 + quad * 8);
        const bf16x8 b0 = *(const bf16x8*)(sB + (wn * 32 + r) * 32 + cs * 8);
        const bf16x8 b1 = *(const bf16x8*)(sB + (wn * 32 + 16 + r) * 32 + cs * 8);
        acc[0] = MFMA(a, b0, acc[0]);
        acc[1] = MFMA(a, b1, acc[1]);
        __syncthreads();
    }

    // --- phase D: epilogue ---
    #pragma unroll
    for (int u = 0; u < 2; u++)
        #pragma unroll
        for (int g = 0; g < 4; g++)
            sC[(wm * 16 + quad * 4 + g) * 66 + wn * 32 + u * 16 + r] = acc[u][g];
    __syncthreads();
    unsigned* dst = (unsigned*)otmp;
    #pragma unroll
    for (int it = 0; it < 4; it++) {
        const int idx = it * 256 + tid;
        const int sr = idx >> 5, jc = idx & 31;
        const float v0 = sC[sr * 66 + jc * 2], v1 = sC[sr * 66 + jc * 2 + 1];
        dst[((long)(b * SEQ + m0 + sr)) * 256 + h * 32 + jc] =
            (unsigned)f2bf(v0) | ((unsigned)f2bf(v1) << 16);
    }
}

// -------------------------------------------------------------------------
extern "C" void kernel_launch(void* const* d_in, const int* in_sizes, int n_in,
                              void* d_out, int out_size, void* d_ws, size_t ws_size,
                              hipStream_t stream) {
    const float* x  = (const float*)d_in[0];
    const float* wq = (const float*)d_in[1];
    const float* bq = (const float*)d_in[2];
    const float* wk = (const float*)d_in[3];
    const float* bk = (const float*)d_in[4];
    const float* wv = (const float*)d_in[5];
    const float* bv = (const float*)d_in[6];
    const float* wo = (const float*)d_in[7];
    const float* bo = (const float*)d_in[8];
    const float* w1 = (const float*)d_in[9];
    const float* b1 = (const float*)d_in[10];
    const float* w2 = (const float*)d_in[11];
    const float* b2 = (const float*)d_in[12];
    float* out = (float*)d_out;

    // ---- workspace layout (~68 MB) ----
    char* wsb = (char*)d_ws;
    float*  scores   = (float*)wsb;                    // 32 MB
    float*  t0       = scores + 8388608;               // 4 MB
    float4* partials = (float4*)(t0 + 1048576);        // 32 KB
    float*  lutbuf   = (float*)(partials + 2048);
    unsigned short* u16 = (unsigned short*)(wsb + (40u << 20));
    unsigned short* x_ext = u16;                       // 3,145,728  [2048,1536]
    unsigned short* w_ext = x_ext + 3145728;           // 2,359,296  [1536,1536]
    unsigned short* q_ext = w_ext + 2359296;           // 3,145,728  [B*H*S,192]
    unsigned short* k_ext = q_ext + 3145728;           // 3,145,728
    unsigned short* vT    = k_ext + 3145728;           // 1,048,576  [B,H,DH,S]
    unsigned short* otmp  = vT + 1048576;              // 1,048,576  [B*S, E]
    unsigned short* woh   = otmp + 1048576;            //   262,144  [E,E]

    // 1) prep: LUT + ext-K split builds
    prep_kernel<<<dim3(9 + 8192), dim3(256), 0, stream>>>(
        x, wq, wk, wv, wo, w1, b1, w2, b2, x_ext, w_ext, woh, lutbuf);

    // 2) fused QKV projection (compensated bf16, K=1536), 3 blocks/CU
    gemm_qkv<<<dim3(24, 32), dim3(256), 0, stream>>>(
        x_ext, w_ext, bq, bk, bv, q_ext, k_ext, vT);

    // 3) scores = q @ k^T per (b,h) (compensated, K=192), clamp
    gemm_scores<<<dim3(4, 8, 32), dim3(256), 0, stream>>>(q_ext, k_ext, scores);

    // 4) autopoietic transform (LUT-based, atomic-free)
    transform_kernel<<<dim3(BATCH * SEQ), dim3(256), 0, stream>>>(
        scores, lutbuf, t0, partials);

    // 5) fused coef + residual/softmax + attn@v (no attn round-trip)
    softmax_attnv<<<dim3(16, 32), dim3(256), 0, stream>>>(
        scores, t0, partials, vT, otmp);

    // 6) out = out_tmp @ wo^T + bo
    gemm_proj<<<dim3(8, 32), dim3(256), 0, stream>>>(otmp, woh, bo, out);
}

// Round 8
// 148.608 us; speedup vs baseline: 2.7107x; 1.1061x over previous
//
#include <hip/hip_runtime.h>
#include <math.h>

// Problem constants (reference: B=4, S=512, E=512, H=8, DH=64, HID=128)
#define BATCH 4
#define SEQ   512
#define EMB   512
#define NH    8
#define DHD   64
#define HIDN  128
#define ALPHA 0.1f
#define EPSS  0.05f

// LUT for the pointwise conv-chain -> sigmoid function of `scaled`
#define LUTN  2048
#define XMIN  (-0.4f)
#define XSTEP (0.8f / LUTN)

typedef __attribute__((ext_vector_type(8))) short  bf16x8;
typedef __attribute__((ext_vector_type(4))) float  f32x4;
#define MFMA(a,b,c) __builtin_amdgcn_mfma_f32_16x16x32_bf16((a),(b),(c),0,0,0)

__device__ __forceinline__ unsigned short f2bf(float f) {
    union { float f; unsigned u; } v; v.f = f;
    unsigned r = v.u + 0x7fffu + ((v.u >> 16) & 1u);   // RNE; inputs finite
    return (unsigned short)(r >> 16);
}
__device__ __forceinline__ float bf2f(unsigned short h) {
    union { unsigned u; float f; } v; v.u = ((unsigned)h) << 16;
    return v.f;
}
__device__ __forceinline__ float f16tof(unsigned short h) {
    union { unsigned short s; _Float16 f; } v; v.s = h; return (float)v.f;
}
__device__ __forceinline__ unsigned short ftof16(float f) {
    union { unsigned short s; _Float16 f; } v; v.f = (_Float16)f; return v.s;
}

// async global->LDS, 16B per lane; LDS dst = uniform base + lane*16
__device__ __forceinline__ void async_lds16(const unsigned short* g, unsigned short* l) {
    __builtin_amdgcn_global_load_lds(
        (const __attribute__((address_space(1))) void*)g,
        (__attribute__((address_space(3))) void*)l, 16, 0, 0);
}

// ---------------- BK=64 GEMM core ----------------------------------------
// NT: C[m,n] = sum_k A[m,k]*B[n,k], row-major bf16, K = KS*64.
// 256 thr / 4 waves as 2x2. MT=64: wave 32 x UN*16; MT=32: wave 16 x UN*16.
// Per K-step: stage MTx64 A + (UN*32)x64 B via global_load_lds (XOR chunk
// swizzle, full 32-bank rows), 1 drain barrier, 2*AF*UN MFMAs, 1 barrier.
template<int KS, int UN, int MT>
__device__ __forceinline__ void gemm_core64(
    const unsigned short* __restrict__ A, const unsigned short* __restrict__ B,
    int m0, int n0, unsigned short* sA, unsigned short* sB, f32x4 (&acc)[2][4])
{
    const int K = KS * 64;
    const int tid = threadIdx.x, w = tid >> 6, lane = tid & 63;
    const int quad = lane >> 4, r = lane & 15;
    const int wm = w >> 1, wn = w & 1;
    const int lrow = lane >> 3, lc = lane & 7;
    const int sc = lc ^ lrow;                     // swizzled global chunk
    constexpr int AF = MT / 32;                   // A frags per wave
    constexpr int NB = UN * 32 / 32;              // B staging calls per wave

    const unsigned short* ag[2]; unsigned short* dAu[2];
    #pragma unroll
    for (int c = 0; c < AF; c++) {
        const int rb = w * (8 * AF) + c * 8;
        ag[c]  = A + (long)(m0 + rb + lrow) * K + sc * 8;
        dAu[c] = sA + rb * 64;
    }
    const unsigned short* bg[4]; unsigned short* dBu[4];
    #pragma unroll
    for (int c = 0; c < NB; c++) {
        const int rb = w * (8 * NB) + c * 8;
        bg[c]  = B + (long)(n0 + rb + lrow) * K + sc * 8;
        dBu[c] = sB + rb * 64;
    }

    for (int s = 0; s < KS; s++) {
        const int k0 = s * 64;
        #pragma unroll
        for (int c = 0; c < AF; c++) async_lds16(ag[c] + k0, dAu[c]);
        #pragma unroll
        for (int c = 0; c < NB; c++) async_lds16(bg[c] + k0, dBu[c]);
        __syncthreads();                          // drain, tile visible
        #pragma unroll
        for (int kc = 0; kc < 2; kc++) {
            bf16x8 af[2], bfr[4];
            #pragma unroll
            for (int t = 0; t < AF; t++) {
                const int row = wm * (16 * AF) + t * 16 + r;
                af[t] = *(const bf16x8*)(sA + row * 64 + ((kc * 4 + quad) ^ (row & 7)) * 8);
            }
            #pragma unroll
            for (int u = 0; u < UN; u++) {
                const int row = wn * (16 * UN) + u * 16 + r;
                bfr[u] = *(const bf16x8*)(sB + row * 64 + ((kc * 4 + quad) ^ (row & 7)) * 8);
            }
            #pragma unroll
            for (int t = 0; t < AF; t++)
                #pragma unroll
                for (int u = 0; u < UN; u++)
                    acc[t][u] = MFMA(af[t], bfr[u], acc[t][u]);
        }
        __syncthreads();                          // protect LDS for next stage
    }
}

// ---------------- fused QKV projection -----------------------------------
// A = x_ext [2048,1536]=[xh|xl|xh]; B = w_ext [1536,1536]=[wh|wh|wl]
// -> exact 3-term compensated product. 64x64 tiles, grid (24,32).
__global__ __launch_bounds__(256) void gemm_qkv(
    const unsigned short* __restrict__ x_ext, const unsigned short* __restrict__ w_ext,
    const float* __restrict__ bq, const float* __restrict__ bk, const float* __restrict__ bv,
    unsigned short* __restrict__ q_ext, unsigned short* __restrict__ k_ext,
    unsigned short* __restrict__ vT)
{
    __shared__ __align__(16) unsigned short sA[64 * 64];
    __shared__ __align__(16) unsigned short sB[64 * 64];
    __shared__ float sC[64 * 68];

    const int m0 = blockIdx.y * 64, n0 = blockIdx.x * 64;
    f32x4 acc[2][4] = {};
    gemm_core64<24, 2, 64>(x_ext, w_ext, m0, n0, sA, sB, acc);

    const int tid = threadIdx.x, w = tid >> 6, lane = tid & 63;
    const int quad = lane >> 4, r = lane & 15;
    const int wm = w >> 1, wn = w & 1;
    #pragma unroll
    for (int t = 0; t < 2; t++)
        #pragma unroll
        for (int u = 0; u < 2; u++)
            #pragma unroll
            for (int g = 0; g < 4; g++)
                sC[(wm * 32 + t * 16 + quad * 4 + g) * 68 + wn * 32 + u * 16 + r] = acc[t][u][g];
    __syncthreads();

    const int which = n0 >> 9;       // 0:q 1:k 2:v
    const int n0l = n0 & 511;        // = h0*64
    const int h0 = n0l >> 6;
    const int b = m0 >> 9, s0 = m0 & 511;

    if (which < 2) {
        const float scl = (which == 0) ? 0.125f : 1.0f;
        const float* bias = (which == 0) ? bq : bk;
        unsigned* dst = (unsigned*)((which == 0) ? q_ext : k_ext);
        #pragma unroll
        for (int seg = 0; seg < 3; seg++) {
            // q_ext row = [hi | lo | hi]; k_ext row = [hi | hi | lo]
            const bool lo = (which == 0) ? (seg == 1) : (seg == 2);
            #pragma unroll
            for (int it = 0; it < 8; it++) {
                const int idx = it * 256 + tid;        // 0..2047
                const int sl = idx >> 5;               // s-row 0..63
                const int jc = idx & 31;               // d pair
                const int nc = jc * 2;
                float v0 = (sC[sl * 68 + nc]     + bias[n0l + nc])     * scl;
                float v1 = (sC[sl * 68 + nc + 1] + bias[n0l + nc + 1]) * scl;
                unsigned short a0 = f2bf(v0), a1 = f2bf(v1);
                if (lo) { a0 = f2bf(v0 - bf2f(a0)); a1 = f2bf(v1 - bf2f(a1)); }
                const long orow = (long)(b * NH + h0) * SEQ + s0 + sl;
                dst[orow * 96 + seg * 32 + jc] = (unsigned)a0 | ((unsigned)a1 << 16);
            }
        }
    } else {
        unsigned* dst = (unsigned*)vT;
        #pragma unroll
        for (int it = 0; it < 8; it++) {
            const int idx = it * 256 + tid;
            const int d = idx >> 5;                    // 0..63
            const int jc = idx & 31;                   // s pair
            const int sl = jc * 2;
            const float bvv = bv[n0l + d];
            const float v0 = sC[sl * 68 + d] + bvv;
            const float v1 = sC[(sl + 1) * 68 + d] + bvv;
            const long orow = (long)(b * NH + h0) * DHD + d;
            dst[orow * 256 + (s0 >> 1) + jc] = (unsigned)f2bf(v0) | ((unsigned)f2bf(v1) << 16);
        }
    }
}

// ---------------- scores = q_ext @ k_ext^T per (b,h), K=192 -> fp16 ------
__global__ __launch_bounds__(256) void gemm_scores(
    const unsigned short* __restrict__ q_ext, const unsigned short* __restrict__ k_ext,
    unsigned short* __restrict__ scoresH)
{
    __shared__ __align__(16) unsigned short sA[64 * 64];
    __shared__ __align__(16) unsigned short sB[128 * 64];
    const int z = blockIdx.z;
    const int m0 = blockIdx.y * 64, n0 = blockIdx.x * 128;
    f32x4 acc[2][4] = {};
    gemm_core64<3, 4, 64>(q_ext + (long)z * SEQ * 192, k_ext + (long)z * SEQ * 192,
                          m0, n0, sA, sB, acc);

    const int tid = threadIdx.x, w = tid >> 6, lane = tid & 63;
    const int quad = lane >> 4, r = lane & 15;
    const int wm = w >> 1, wn = w & 1;
    // pack fp16 tile into LDS (reuse sB: 64x128 halves = 16 KB), then 16B stores
    unsigned short* hC = sB;
    #pragma unroll
    for (int t = 0; t < 2; t++)
        #pragma unroll
        for (int u = 0; u < 4; u++)
            #pragma unroll
            for (int g = 0; g < 4; g++) {
                const int ml = wm * 32 + t * 16 + quad * 4 + g;
                const int nl = wn * 64 + u * 16 + r;
                hC[ml * 128 + nl] = ftof16(fminf(fmaxf(acc[t][u][g], -15.f), 15.f));
            }
    __syncthreads();
    #pragma unroll
    for (int it = 0; it < 4; it++) {
        const int id = it * 256 + tid;       // 0..1023
        const int ml = id >> 4, ch = id & 15;
        *(uint4*)(scoresH + ((long)z * SEQ + m0 + ml) * SEQ + n0 + ch * 8) =
            *(const uint4*)(hC + ml * 128 + ch * 8);
    }
}

// ---------------- out = out_tmp @ wo^T + bo (32x64 tiles) ----------------
__global__ __launch_bounds__(256) void gemm_proj(
    const unsigned short* __restrict__ otmp, const unsigned short* __restrict__ woh,
    const float* __restrict__ bo, float* __restrict__ out)
{
    __shared__ __align__(16) unsigned short sA[32 * 64];
    __shared__ __align__(16) unsigned short sB[64 * 64];
    const int m0 = blockIdx.y * 32, n0 = blockIdx.x * 64;
    f32x4 acc[2][4] = {};
    gemm_core64<8, 2, 32>(otmp, woh, m0, n0, sA, sB, acc);
    const int tid = threadIdx.x, w = tid >> 6, lane = tid & 63;
    const int quad = lane >> 4, r = lane & 15;
    const int wm = w >> 1, wn = w & 1;
    #pragma unroll
    for (int u = 0; u < 2; u++)
        #pragma unroll
        for (int g = 0; g < 4; g++) {
            const int m = m0 + wm * 16 + quad * 4 + g;
            const int n = n0 + wn * 32 + u * 16 + r;
            out[(long)m * EMB + n] = acc[0][u][g] + bo[n];
        }
}

// ---------------- block reduction helpers (blockDim=256, 4 waves) --------
__device__ __forceinline__ float blockReduceSum(float v, float* sred) {
    #pragma unroll
    for (int o = 32; o > 0; o >>= 1) v += __shfl_down(v, o);
    __syncthreads();
    if ((threadIdx.x & 63) == 0) sred[threadIdx.x >> 6] = v;
    __syncthreads();
    return (sred[0] + sred[1]) + (sred[2] + sred[3]);
}
__device__ __forceinline__ float blockReduceMax(float v, float* sred) {
    #pragma unroll
    for (int o = 32; o > 0; o >>= 1) v = fmaxf(v, __shfl_down(v, o));
    __syncthreads();
    if ((threadIdx.x & 63) == 0) sred[threadIdx.x >> 6] = v;
    __syncthreads();
    return fmaxf(fmaxf(sred[0], sred[1]), fmaxf(sred[2], sred[3]));
}

// ---------------- fused prep: LUT + ext-K split builds -------------------
__global__ __launch_bounds__(256) void prep_kernel(
    const float* __restrict__ x,
    const float* __restrict__ wq, const float* __restrict__ wk,
    const float* __restrict__ wv, const float* __restrict__ wo,
    const float* __restrict__ w1, const float* __restrict__ b1,
    const float* __restrict__ w2, const float* __restrict__ b2,
    unsigned short* __restrict__ x_ext, unsigned short* __restrict__ w_ext,
    unsigned short* __restrict__ woh, float* __restrict__ lut)
{
    const int blk = blockIdx.x;
    if (blk < 9) {
        const int i = blk * 256 + threadIdx.x;
        if (i > LUTN) return;
        const float xv = XMIN + i * XSTEP;
        float a = 0.f;
        for (int h = 0; h < HIDN; h++) {
            float hv = xv * w1[h] + b1[h];
            hv = fminf(fmaxf(hv, -5.f), 5.f);
            hv = fmaxf(hv, 0.f);
            a += hv * w2[h];
        }
        a += b2[0];
        a = fminf(fmaxf(a, -5.f), 5.f);
        const float taylor = fminf(fmaxf(1.f + 2.5f * a, 0.5f), 1.5f);
        lut[i] = 1.f / (1.f + expf(-taylor));
        return;
    }
    const int i = (blk - 9) * 256 + threadIdx.x;  // 0 .. 2097151
    if (i < 1048576) {
        const int m = i >> 9, k = i & 511;
        const float v = x[i];
        const unsigned short h = f2bf(v), l = f2bf(v - bf2f(h));
        const long bb = (long)m * 1536 + k;
        x_ext[bb] = h; x_ext[bb + 512] = l; x_ext[bb + 1024] = h;   // [xh|xl|xh]
    } else if (i < 1835008) {
        const int j = i - 1048576;
        const int n = j >> 9, k = j & 511;
        const float v = (j < 262144) ? wq[j] : (j < 524288 ? wk[j - 262144] : wv[j - 524288]);
        const unsigned short h = f2bf(v), l = f2bf(v - bf2f(h));
        const long bb = (long)n * 1536 + k;
        w_ext[bb] = h; w_ext[bb + 512] = h; w_ext[bb + 1024] = l;   // [wh|wh|wl]
    } else {
        const int j = i - 1835008;
        woh[j] = f2bf(wo[j]);
    }
}

// ---------------- transform kernel: one block per (b,i) row --------------
__global__ __launch_bounds__(256) void transform_kernel(
    const unsigned short* __restrict__ scoresH, // [B,H,S,S] fp16 (clamped)
    const float* __restrict__ lut,              // [LUTN+1]
    unsigned short* __restrict__ t0H,           // [B,S,S] fp16
    float4* __restrict__ partials)              // [B*S] float4 slots
{
    const int rr = blockIdx.x;
    const int b = rr >> 9, i = rr & 511;
    const int tid = threadIdx.x;

    __shared__ float slut[LUTN + 1];
    __shared__ float sred[4];

    for (int u = tid; u <= LUTN; u += 256) slut[u] = lut[u];

    // mean over heads: packed fp16 pair loads (j = 2*tid, 2*tid+1)
    const unsigned* baseU =
        (const unsigned*)(scoresH + (((long)(b * NH)) * SEQ + i) * SEQ) + tid;
    float s0 = 0.f, s1 = 0.f;
    #pragma unroll
    for (int h = 0; h < NH; h++) {
        const unsigned pv = baseU[h * (SEQ * SEQ / 2)];
        s0 += f16tof((unsigned short)pv);
        s1 += f16tof((unsigned short)(pv >> 16));
    }
    float mv[2] = { s0 * 0.125f, s1 * 0.125f };
    __syncthreads();

    float sigv[2], mclip[2];
    float lmax = -1e30f;
    #pragma unroll
    for (int u = 0; u < 2; u++) {
        const float m = mv[u];
        const float x = fminf(fmaxf(m, -8.f), 8.f) * EPSS;
        float t = (x - XMIN) * (1.0f / XSTEP);
        int idx = (int)t;
        idx = idx < 0 ? 0 : (idx > LUTN - 1 ? LUTN - 1 : idx);
        const float frac = t - (float)idx;
        const float l0 = slut[idx], l1 = slut[idx + 1];
        sigv[u] = l0 + frac * (l1 - l0);
        const float mc = fminf(fmaxf(m, -10.f), 10.f);
        mclip[u] = mc;
        lmax = fmaxf(lmax, mc);
    }

    const float rmax = blockReduceMax(lmax, sred);
    float ex[2], lsum = 0.f;
    #pragma unroll
    for (int u = 0; u < 2; u++) { ex[u] = expf(mclip[u] - rmax); lsum += ex[u]; }
    const float rsum = blockReduceSum(lsum, sred);
    const float inv = 1.f / rsum;

    float hent[2], lmax2 = -1e30f;
    #pragma unroll
    for (int u = 0; u < 2; u++) {
        const float p = ex[u] * inv;
        const float he = -p * logf(p + 1e-6f);
        hent[u] = 3.f * he;
        lmax2 = fmaxf(lmax2, hent[u]);
    }
    const float rmax2 = blockReduceMax(lmax2, sred);
    float ex2[2], lsum2 = 0.f;
    #pragma unroll
    for (int u = 0; u < 2; u++) { ex2[u] = expf(hent[u] - rmax2); lsum2 += ex2[u]; }
    const float rsum2 = blockReduceSum(lsum2, sred);
    const float inv2 = 1.f / rsum2;

    float tv[2];
    #pragma unroll
    for (int u = 0; u < 2; u++) tv[u] = sigv[u] * (ex2[u] * inv2);
    ((unsigned*)t0H)[((long)b * SEQ + i) * (SEQ / 2) + tid] =
        (unsigned)ftof16(tv[0]) | ((unsigned)ftof16(tv[1]) << 16);

    float s_m  = blockReduceSum(mv[0] + mv[1], sred);
    float s_m2 = blockReduceSum(mv[0] * mv[0] + mv[1] * mv[1], sred);
    float s_t  = blockReduceSum(tv[0] + tv[1], sred);
    float s_t2 = blockReduceSum(tv[0] * tv[0] + tv[1] * tv[1], sred);
    if (tid == 0) partials[rr] = make_float4(s_m, s_m2, s_t, s_t2);
}

// ---------------- fused coef + softmax + attn@v --------------------------
// Grid (16 m-tiles of 32 rows, 32 z=(b,h)).
__global__ __launch_bounds__(256) void softmax_attnv(
    const unsigned short* __restrict__ scoresH, // [B,H,S,S] fp16
    const unsigned short* __restrict__ t0H,     // [B,S,S] fp16
    const float4* __restrict__ partials,        // [B*S]
    const unsigned short* __restrict__ vT,      // [B,H,DH,S] bf16
    unsigned short* __restrict__ otmp)          // [B*S, E] bf16
{
    __shared__ __align__(16) unsigned short attnS[32 * 520];  // bf16, +8 pad
    __shared__ __align__(16) unsigned short sB[64 * 64];
    __shared__ float sC[32 * 66];
    __shared__ float sred[4];

    const int m0 = blockIdx.x * 32;
    const int z  = blockIdx.y;
    const int b  = z >> 3, h = z & 7;
    const int tid = threadIdx.x, wv = tid >> 6, lane = tid & 63;

    // --- phase A: coef (redundant per block) ---
    const float4 p0 = partials[b * SEQ + tid];
    const float4 p1 = partials[b * SEQ + tid + 256];
    float sm  = blockReduceSum(p0.x + p1.x, sred);
    float sm2 = blockReduceSum(p0.y + p1.y, sred);
    float st  = blockReduceSum(p0.z + p1.z, sred);
    float st2 = blockReduceSum(p0.w + p1.w, sred);
    const float n = (float)SEQ * (float)SEQ;
    const float gamma = fminf(fmaxf((sqrtf(sm2) + 1e-4f) / (sqrtf(st2) + 1e-4f), 0.8f), 1.2f);
    const float o_mean = sm / n, t0m = st / n;
    const float o_std = sqrtf(fmaxf(fmaxf(sm2 / n - o_mean * o_mean, 0.f), 0.01f));
    const float t_std = sqrtf(fmaxf(gamma * gamma * fmaxf(st2 / n - t0m * t0m, 0.f), 0.01f));
    const float gdyn = fminf(fmaxf(o_std / t_std, 0.8f), 1.2f);
    const float c1 = gdyn * gamma;
    const float c0 = o_mean - c1 * t0m;

    // --- phase B: softmax 32 rows -> LDS bf16 tile ---
    const int j0 = lane * 8;
    for (int it = 0; it < 8; it++) {
        const int rowl = it * 4 + wv;
        const bf16x8 sr = *(const bf16x8*)(scoresH + ((long)z * SEQ + m0 + rowl) * SEQ + j0);
        const bf16x8 tr = *(const bf16x8*)(t0H + ((long)b * SEQ + m0 + rowl) * SEQ + j0);
        float sv[8];
        float lmax = -1e30f;
        #pragma unroll
        for (int u = 0; u < 8; u++) {
            float s = f16tof((unsigned short)sr[u])
                    + ALPHA * (c0 + c1 * f16tof((unsigned short)tr[u]));
            s = fminf(fmaxf(s, -15.f), 15.f);
            sv[u] = s;
            lmax = fmaxf(lmax, s);
        }
        #pragma unroll
        for (int o = 32; o > 0; o >>= 1) lmax = fmaxf(lmax, __shfl_down(lmax, o));
        lmax = __shfl(lmax, 0);
        float lsum = 0.f;
        #pragma unroll
        for (int u = 0; u < 8; u++) { sv[u] = expf(sv[u] - lmax); lsum += sv[u]; }
        #pragma unroll
        for (int o = 32; o > 0; o >>= 1) lsum += __shfl_down(lsum, o);
        lsum = __shfl(lsum, 0);
        const float inv = 1.f / lsum;
        bf16x8 pk;
        #pragma unroll
        for (int u = 0; u < 8; u++) pk[u] = (short)f2bf(sv[u] * inv);
        *(bf16x8*)(attnS + rowl * 520 + j0) = pk;
    }
    __syncthreads();

    // --- phase C: attn(LDS) @ vT(staged, BK=64) ---
    const int quad = lane >> 4, r = lane & 15;
    const int wm = wv >> 1, wn = wv & 1;
    const int lrow = lane >> 3, lc = lane & 7;
    const int sc = lc ^ lrow;
    const unsigned short* bg0 = vT + (long)z * DHD * SEQ + (long)(wv * 16 + lrow) * SEQ + sc * 8;
    const unsigned short* bg1 = bg0 + 8 * SEQ;
    unsigned short* dB0 = sB + (wv * 16) * 64;
    unsigned short* dB1 = sB + (wv * 16 + 8) * 64;
    f32x4 acc[2] = {};
    for (int s = 0; s < 8; s++) {
        const int k0 = s * 64;
        async_lds16(bg0 + k0, dB0);
        async_lds16(bg1 + k0, dB1);
        __syncthreads();
        #pragma unroll
        for (int kc = 0; kc < 2; kc++) {
            const bf16x8 a = *(const bf16x8*)(attnS + (wm * 16 + r) * 520 + k0 + kc * 32 + quad * 8);
            #pragma unroll
            for (int u = 0; u < 2; u++) {
                const int row = wn * 32 + u * 16 + r;
                const bf16x8 bb = *(const bf16x8*)(sB + row * 64 + ((kc * 4 + quad) ^ (row & 7)) * 8);
                acc[u] = MFMA(a, bb, acc[u]);
            }
        }
        __syncthreads();
    }

    // --- phase D: epilogue ---
    #pragma unroll
    for (int u = 0; u < 2; u++)
        #pragma unroll
        for (int g = 0; g < 4; g++)
            sC[(wm * 16 + quad * 4 + g) * 66 + wn * 32 + u * 16 + r] = acc[u][g];
    __syncthreads();
    unsigned* dst = (unsigned*)otmp;
    #pragma unroll
    for (int it = 0; it < 4; it++) {
        const int idx = it * 256 + tid;
        const int sr2 = idx >> 5, jc = idx & 31;
        const float v0 = sC[sr2 * 66 + jc * 2], v1 = sC[sr2 * 66 + jc * 2 + 1];
        dst[((long)(b * SEQ + m0 + sr2)) * 256 + h * 32 + jc] =
            (unsigned)f2bf(v0) | ((unsigned)f2bf(v1) << 16);
    }
}

// -------------------------------------------------------------------------
extern "C" void kernel_launch(void* const* d_in, const int* in_sizes, int n_in,
                              void* d_out, int out_size, void* d_ws, size_t ws_size,
                              hipStream_t stream) {
    const float* x  = (const float*)d_in[0];
    const float* wq = (const float*)d_in[1];
    const float* bq = (const float*)d_in[2];
    const float* wk = (const float*)d_in[3];
    const float* bk = (const float*)d_in[4];
    const float* wv = (const float*)d_in[5];
    const float* bv = (const float*)d_in[6];
    const float* wo = (const float*)d_in[7];
    const float* bo = (const float*)d_in[8];
    const float* w1 = (const float*)d_in[9];
    const float* b1 = (const float*)d_in[10];
    const float* w2 = (const float*)d_in[11];
    const float* b2 = (const float*)d_in[12];
    float* out = (float*)d_out;

    // ---- workspace layout (~48 MB) ----
    char* wsb = (char*)d_ws;
    unsigned short* scoresH = (unsigned short*)wsb;        // 16 MB [B,H,S,S] fp16
    unsigned short* t0H     = scoresH + 8388608;           // 2 MB  [B,S,S] fp16
    float4* partials = (float4*)(t0H + 1048576);           // 32 KB
    float*  lutbuf   = (float*)(partials + 2048);
    unsigned short* u16 = (unsigned short*)(wsb + (20u << 20));
    unsigned short* x_ext = u16;                           // 6 MB   [2048,1536]
    unsigned short* w_ext = x_ext + 3145728;               // 4.5 MB [1536,1536]
    unsigned short* q_ext = w_ext + 2359296;               // 6 MB   [B*H*S,192]
    unsigned short* k_ext = q_ext + 3145728;               // 6 MB
    unsigned short* vT    = k_ext + 3145728;               // 2 MB   [B,H,DH,S]
    unsigned short* otmp  = vT + 1048576;                  // 2 MB   [B*S, E]
    unsigned short* woh   = otmp + 1048576;                // 0.5 MB [E,E]

    // 1) prep: LUT + ext-K split builds
    prep_kernel<<<dim3(9 + 8192), dim3(256), 0, stream>>>(
        x, wq, wk, wv, wo, w1, b1, w2, b2, x_ext, w_ext, woh, lutbuf);

    // 2) fused QKV projection (compensated bf16, K=1536, BK=64)
    gemm_qkv<<<dim3(24, 32), dim3(256), 0, stream>>>(
        x_ext, w_ext, bq, bk, bv, q_ext, k_ext, vT);

    // 3) scores = q @ k^T per (b,h) (compensated, K=192) -> fp16, clamp
    gemm_scores<<<dim3(4, 8, 32), dim3(256), 0, stream>>>(q_ext, k_ext, scoresH);

    // 4) autopoietic transform (LUT-based, atomic-free, fp16 I/O)
    transform_kernel<<<dim3(BATCH * SEQ), dim3(256), 0, stream>>>(
        scoresH, lutbuf, t0H, partials);

    // 5) fused coef + residual/softmax + attn@v (fp16 in, BK=64)
    softmax_attnv<<<dim3(16, 32), dim3(256), 0, stream>>>(
        scoresH, t0H, partials, vT, otmp);

    // 6) out = out_tmp @ wo^T + bo (32x64 tiles, 512 blocks)
    gemm_proj<<<dim3(8, 64), dim3(256), 0, stream>>>(otmp, woh, bo, out);
}